// Round 1
// baseline (1251.227 us; speedup 1.0000x reference)
//
#include <hip/hip_runtime.h>
#include <hip/hip_bf16.h>

// GCN: conv1(512->16) + relu + conv2(16->5) + mlp(5->32->5) + log_softmax
// out[dst] = dinv[dst]*(sum_{src in N(dst)} hs[src] + hs[dst]) + b,  hs = dinv*(h@W)

#define F_IN 512
#define HDIM 16
#define CDIM 5

__device__ inline float bf2f(unsigned short u){
  unsigned int i = ((unsigned int)u) << 16; float f; __builtin_memcpy(&f, &i, 4); return f;
}
__device__ inline unsigned short f2bf(float x){
  unsigned int i; __builtin_memcpy(&i, &x, 4);
  unsigned int r = i + 0x7FFFu + ((i >> 16) & 1u);
  return (unsigned short)(r >> 16);
}

// ---- detect int64 vs int32 edge_index layout: odd 32-bit words all zero => int64
__global__ void k_detect(const int* __restrict__ ei, int* __restrict__ flag, int E){
  int k = blockIdx.x * blockDim.x + threadIdx.x;           // 2048 threads
  long long step = E / 2048; if (step < 1) step = 1;
  long long pos = 2LL * ((long long)k * step) + 1;
  if (pos < 2LL * E){
    if (ei[pos] != 0) atomicOr(flag, 1);                   // any nonzero odd word => int32
  }
}

// ---- in-degree histogram over dst
__global__ void k_hist(const int* __restrict__ ei, const int* __restrict__ flag,
                       int* __restrict__ cnt, int E){
  int e = blockIdx.x * blockDim.x + threadIdx.x;
  if (e >= E) return;
  int is32 = *flag;
  int stride = is32 ? 1 : 2;
  size_t dstoff = is32 ? (size_t)E : (size_t)2 * E;
  int dst = ei[dstoff + (size_t)e * stride];
  atomicAdd(&cnt[dst], 1);
}

// ---- single-block exclusive scan (N=100k, ~98 iters) + dinv
__global__ __launch_bounds__(1024) void k_scan(const int* __restrict__ cnt, int* __restrict__ rowptr,
                                               int* __restrict__ wp, float* __restrict__ dinv, int n){
  __shared__ int wsum[16];
  __shared__ int carry_s;
  int t = threadIdx.x, lane = t & 63, w = t >> 6;
  if (t == 0) carry_s = 0;
  __syncthreads();
  for (int base = 0; base < n; base += 1024){
    int i = base + t;
    int v = (i < n) ? cnt[i] : 0;
    int xs = v;
    #pragma unroll
    for (int off = 1; off < 64; off <<= 1){
      int y = __shfl_up(xs, off);
      if (lane >= off) xs += y;
    }
    if (lane == 63) wsum[w] = xs;
    __syncthreads();
    int woff = 0;
    for (int k = 0; k < w; ++k) woff += wsum[k];
    int carry = carry_s;
    if (i < n){
      int excl = carry + woff + xs - v;
      rowptr[i] = excl; wp[i] = excl;
      dinv[i] = rsqrtf((float)(v + 1));                    // +1 self loop
    }
    __syncthreads();
    if (t == 1023) carry_s = carry + woff + xs;
    __syncthreads();
  }
  if (t == 0) rowptr[n] = carry_s;
}

// ---- bucket srcs by dst (CSR fill)
__global__ void k_fill(const int* __restrict__ ei, const int* __restrict__ flag,
                       int* __restrict__ wp, int* __restrict__ ssrc, int E){
  int e = blockIdx.x * blockDim.x + threadIdx.x;
  if (e >= E) return;
  int is32 = *flag;
  int stride = is32 ? 1 : 2;
  size_t dstoff = is32 ? (size_t)E : (size_t)2 * E;
  int src = ei[(size_t)e * stride];
  int dst = ei[dstoff + (size_t)e * stride];
  int pos = atomicAdd(&wp[dst], 1);
  ssrc[pos] = src;
}

// ---- hs1 = dinv * (x @ W1), stored bf16 [N][16]. one thread per row.
__global__ __launch_bounds__(256) void k_gemm1(const float* __restrict__ x, const float* __restrict__ W1,
                                               const float* __restrict__ dinv, unsigned short* __restrict__ hs1,
                                               int n){
  int r = blockIdx.x * blockDim.x + threadIdx.x;
  if (r >= n) return;
  const float4* xr = (const float4*)(x + (size_t)r * F_IN);
  float acc[HDIM];
  #pragma unroll
  for (int j = 0; j < HDIM; ++j) acc[j] = 0.f;
  for (int k4 = 0; k4 < F_IN / 4; ++k4){
    float4 v = xr[k4];
    const float* w = W1 + k4 * 4 * HDIM;                   // uniform index -> s_load
    #pragma unroll
    for (int j = 0; j < HDIM; ++j) acc[j] = fmaf(v.x, w[j], acc[j]);
    #pragma unroll
    for (int j = 0; j < HDIM; ++j) acc[j] = fmaf(v.y, w[HDIM + j], acc[j]);
    #pragma unroll
    for (int j = 0; j < HDIM; ++j) acc[j] = fmaf(v.z, w[2 * HDIM + j], acc[j]);
    #pragma unroll
    for (int j = 0; j < HDIM; ++j) acc[j] = fmaf(v.w, w[3 * HDIM + j], acc[j]);
  }
  float dv = dinv[r];
  unsigned short o[HDIM];
  #pragma unroll
  for (int j = 0; j < HDIM; ++j) o[j] = f2bf(dv * acc[j]);
  uint4 v0, v1;
  __builtin_memcpy(&v0, o, 16);
  __builtin_memcpy(&v1, o + 8, 16);
  uint4* dst = (uint4*)(hs1 + (size_t)r * HDIM);
  dst[0] = v0; dst[1] = v1;
}

// ---- conv1 aggregate + b1 + relu + @W2 + dinv scale -> hs2 bf16 [N][8]
// wave per node; lane = (s:2 edge-slot, j:4 feature)
__global__ __launch_bounds__(256) void k_agg1(const unsigned short* __restrict__ hs1,
    const int* __restrict__ rowptr, const int* __restrict__ ssrc,
    const float* __restrict__ dinv, const float* __restrict__ b1,
    const float* __restrict__ W2, unsigned short* __restrict__ hs2, int n){
  int lane = threadIdx.x & 63;
  int i = blockIdx.x * 4 + (threadIdx.x >> 6);
  if (i >= n) return;
  int s = lane >> 4, j = lane & 15;
  int beg = rowptr[i], end = rowptr[i + 1];
  float acc = 0.f;
  for (int e = beg + s; e < end; e += 4){
    int src = ssrc[e];
    acc += bf2f(hs1[(size_t)src * HDIM + j]);
  }
  acc += __shfl_xor(acc, 16);
  acc += __shfl_xor(acc, 32);
  float dv = dinv[i];
  float r = fmaxf(fmaf(dv, acc + bf2f(hs1[(size_t)i * HDIM + j]), b1[j]), 0.f);
  float p0 = r * W2[j * CDIM + 0], p1 = r * W2[j * CDIM + 1], p2 = r * W2[j * CDIM + 2];
  float p3 = r * W2[j * CDIM + 3], p4 = r * W2[j * CDIM + 4];
  #pragma unroll
  for (int off = 1; off < 16; off <<= 1){
    p0 += __shfl_xor(p0, off); p1 += __shfl_xor(p1, off); p2 += __shfl_xor(p2, off);
    p3 += __shfl_xor(p3, off); p4 += __shfl_xor(p4, off);
  }
  if (lane == 0){
    unsigned short o[8];
    o[0] = f2bf(dv * p0); o[1] = f2bf(dv * p1); o[2] = f2bf(dv * p2);
    o[3] = f2bf(dv * p3); o[4] = f2bf(dv * p4);
    o[5] = 0; o[6] = 0; o[7] = 0;
    uint4 v; __builtin_memcpy(&v, o, 16);
    *(uint4*)(hs2 + (size_t)i * 8) = v;
  }
}

// ---- conv2 aggregate + b2 + mlp(W3,b3 relu, W4,b4) + log_softmax -> out [N][5] f32
// wave per node; lane = (t:3 edge-slot, j:3 feature of 8)
__global__ __launch_bounds__(256) void k_agg2(const unsigned short* __restrict__ hs2,
    const int* __restrict__ rowptr, const int* __restrict__ ssrc,
    const float* __restrict__ dinv, const float* __restrict__ b2,
    const float* __restrict__ W3, const float* __restrict__ b3,
    const float* __restrict__ W4, const float* __restrict__ b4,
    float* __restrict__ out, int n){
  int lane = threadIdx.x & 63;
  int i = blockIdx.x * 4 + (threadIdx.x >> 6);
  if (i >= n) return;
  int t = lane >> 3, j = lane & 7;
  int beg = rowptr[i], end = rowptr[i + 1];
  float acc = 0.f;
  for (int e = beg + t; e < end; e += 8){
    int src = ssrc[e];
    acc += bf2f(hs2[(size_t)src * 8 + j]);
  }
  acc += __shfl_xor(acc, 8);
  acc += __shfl_xor(acc, 16);
  acc += __shfl_xor(acc, 32);
  float dv = dinv[i];
  float a2 = dv * (acc + bf2f(hs2[(size_t)i * 8 + j])) + ((j < CDIM) ? b2[j] : 0.f);
  float a0 = __shfl(a2, 0), a1 = __shfl(a2, 1), a2b = __shfl(a2, 2), a3 = __shfl(a2, 3), a4 = __shfl(a2, 4);
  int m = lane & 31;
  float h3 = b3[m];
  h3 = fmaf(a0, W3[0 * 32 + m], h3);
  h3 = fmaf(a1, W3[1 * 32 + m], h3);
  h3 = fmaf(a2b, W3[2 * 32 + m], h3);
  h3 = fmaf(a3, W3[3 * 32 + m], h3);
  h3 = fmaf(a4, W3[4 * 32 + m], h3);
  h3 = fmaxf(h3, 0.f);
  float q0 = h3 * W4[m * CDIM + 0], q1 = h3 * W4[m * CDIM + 1], q2 = h3 * W4[m * CDIM + 2];
  float q3 = h3 * W4[m * CDIM + 3], q4 = h3 * W4[m * CDIM + 4];
  #pragma unroll
  for (int off = 1; off < 32; off <<= 1){
    q0 += __shfl_xor(q0, off); q1 += __shfl_xor(q1, off); q2 += __shfl_xor(q2, off);
    q3 += __shfl_xor(q3, off); q4 += __shfl_xor(q4, off);
  }
  q0 += b4[0]; q1 += b4[1]; q2 += b4[2]; q3 += b4[3]; q4 += b4[4];
  float mx = fmaxf(fmaxf(fmaxf(q0, q1), fmaxf(q2, q3)), q4);
  float sum = expf(q0 - mx) + expf(q1 - mx) + expf(q2 - mx) + expf(q3 - mx) + expf(q4 - mx);
  float lse = mx + logf(sum);
  if (lane < CDIM){
    float v = q0;
    if (lane == 1) v = q1;
    if (lane == 2) v = q2;
    if (lane == 3) v = q3;
    if (lane == 4) v = q4;
    out[(size_t)i * CDIM + lane] = v - lse;
  }
}

extern "C" void kernel_launch(void* const* d_in, const int* in_sizes, int n_in,
                              void* d_out, int out_size, void* d_ws, size_t ws_size,
                              hipStream_t stream){
  const float* x  = (const float*)d_in[0];
  const int*   ei = (const int*)d_in[1];
  const float* W1 = (const float*)d_in[2];
  const float* b1 = (const float*)d_in[3];
  const float* W2 = (const float*)d_in[4];
  const float* b2 = (const float*)d_in[5];
  const float* W3 = (const float*)d_in[6];
  const float* b3 = (const float*)d_in[7];
  const float* W4 = (const float*)d_in[8];
  const float* b4 = (const float*)d_in[9];
  float* out = (float*)d_out;

  int N = in_sizes[0] / F_IN;
  int E = in_sizes[1] / 2;

  char* ws = (char*)d_ws;
  size_t off = 0;
  auto alloc = [&](size_t bytes) -> char* {
    char* p = ws + off;
    off += (bytes + 255) & ~(size_t)255;
    return p;
  };
  int* cnt   = (int*)alloc((size_t)N * 4 + 4);   // flag lives at cnt[N]
  int* flag  = cnt + N;
  int* rowptr= (int*)alloc(((size_t)N + 1) * 4);
  int* wp    = (int*)alloc((size_t)N * 4);
  float* dinv= (float*)alloc((size_t)N * 4);
  int* ssrc  = (int*)alloc((size_t)E * 4);
  unsigned short* hs1 = (unsigned short*)alloc((size_t)N * HDIM * 2);
  unsigned short* hs2 = (unsigned short*)alloc((size_t)N * 8 * 2);
  (void)ws_size; (void)n_in; (void)out_size;

  hipMemsetAsync(cnt, 0, (size_t)N * 4 + 4, stream);
  k_detect<<<8, 256, 0, stream>>>(ei, flag, E);
  k_hist<<<(E + 255) / 256, 256, 0, stream>>>(ei, flag, cnt, E);
  k_scan<<<1, 1024, 0, stream>>>(cnt, rowptr, wp, dinv, N);
  k_fill<<<(E + 255) / 256, 256, 0, stream>>>(ei, flag, wp, ssrc, E);
  k_gemm1<<<(N + 255) / 256, 256, 0, stream>>>(x, W1, dinv, hs1, N);
  k_agg1<<<(N + 3) / 4, 256, 0, stream>>>(hs1, rowptr, ssrc, dinv, b1, W2, hs2, N);
  k_agg2<<<(N + 3) / 4, 256, 0, stream>>>(hs2, rowptr, ssrc, dinv, b2, W3, b3, W4, b4, out, N);
}

// Round 2
// 531.395 us; speedup vs baseline: 2.3546x; 2.3546x over previous
//
#include <hip/hip_runtime.h>
#include <hip/hip_bf16.h>

// GCN: conv1(512->16) + relu + conv2(16->5) + mlp(5->32->5) + log_softmax
// out[dst] = dinv[dst]*(sum_{src in N(dst)} hs[src] + hs[dst]) + b,  hs = dinv*(h@W)
// CSR build via 2-level binning (1024 dst-range buckets) to avoid random 4B scatter.

#define F_IN 512
#define HDIM 16
#define CDIM 5
#define NB   1024      // dst-range buckets
#define SCAT_BLOCKS 128
#define CAP  8192      // per-bucket LDS staging (ints); fallback to direct store if exceeded

__device__ inline float bf2f(unsigned short u){
  unsigned int i = ((unsigned int)u) << 16; float f; __builtin_memcpy(&f, &i, 4); return f;
}
__device__ inline unsigned short f2bf(float x){
  unsigned int i; __builtin_memcpy(&i, &x, 4);
  unsigned int r = i + 0x7FFFu + ((i >> 16) & 1u);
  return (unsigned short)(r >> 16);
}

// ---- detect int64 vs int32 edge_index layout: odd 32-bit words all zero => int64
__global__ void k_detect(const int* __restrict__ ei, int* __restrict__ flag, int E){
  int k = blockIdx.x * blockDim.x + threadIdx.x;
  long long step = E / 2048; if (step < 1) step = 1;
  long long pos = 2LL * ((long long)k * step) + 1;
  if (pos < 2LL * E){
    if (ei[pos] != 0) atomicOr(flag, 1);                   // nonzero odd word => int32
  }
}

// ---- per-bucket histogram (LDS-staged)
__global__ __launch_bounds__(256) void k_binhist(const int* __restrict__ ei, const int* __restrict__ flag,
                                                 int* __restrict__ bhist, int E, int NPB){
  __shared__ int h[NB];
  for (int k = threadIdx.x; k < NB; k += 256) h[k] = 0;
  __syncthreads();
  int is32 = *flag;
  int stride = is32 ? 1 : 2;
  size_t doff = is32 ? (size_t)E : (size_t)2 * E;
  for (long long e = blockIdx.x * blockDim.x + threadIdx.x; e < E;
       e += (long long)gridDim.x * blockDim.x){
    int dst = ei[doff + (size_t)e * stride];
    atomicAdd(&h[dst / NPB], 1);
  }
  __syncthreads();
  for (int k = threadIdx.x; k < NB; k += 256){
    int v = h[k];
    if (v) atomicAdd(&bhist[k], v);
  }
}

// ---- exclusive scan over NB buckets -> bbase, gwp
__global__ __launch_bounds__(1024) void k_scanNB(const int* __restrict__ cnt, int* __restrict__ bbase,
                                                 int* __restrict__ gwp, int nb){
  __shared__ int wsum[16];
  __shared__ int carry_s;
  int t = threadIdx.x, lane = t & 63, w = t >> 6;
  if (t == 0) carry_s = 0;
  __syncthreads();
  for (int base = 0; base < nb; base += 1024){
    int i = base + t;
    int v = (i < nb) ? cnt[i] : 0;
    int xs = v;
    #pragma unroll
    for (int off = 1; off < 64; off <<= 1){
      int y = __shfl_up(xs, off);
      if (lane >= off) xs += y;
    }
    if (lane == 63) wsum[w] = xs;
    __syncthreads();
    int woff = 0;
    for (int k = 0; k < w; ++k) woff += wsum[k];
    int carry = carry_s;
    if (i < nb){
      int excl = carry + woff + xs - v;
      bbase[i] = excl; gwp[i] = excl;
    }
    __syncthreads();
    if (t == 1023) carry_s = carry + woff + xs;
    __syncthreads();
  }
  if (t == 0) bbase[nb] = carry_s;
}

// ---- chunked scatter: each block reserves per-bucket runs, writes packed src|dl<<20
__global__ __launch_bounds__(256) void k_binscatter(const int* __restrict__ ei, const int* __restrict__ flag,
                                                    int* __restrict__ gwp, int* __restrict__ pairs,
                                                    int E, int NPB){
  __shared__ int bh[NB];
  __shared__ int bb2[NB];
  int t = threadIdx.x;
  int chunk = (E + gridDim.x - 1) / gridDim.x;
  int e0 = blockIdx.x * chunk;
  int e1 = min(E, e0 + chunk);
  int is32 = *flag;
  int stride = is32 ? 1 : 2;
  size_t doff = is32 ? (size_t)E : (size_t)2 * E;
  for (int k = t; k < NB; k += 256) bh[k] = 0;
  __syncthreads();
  for (int e = e0 + t; e < e1; e += 256){
    int dst = ei[doff + (size_t)e * stride];
    atomicAdd(&bh[dst / NPB], 1);
  }
  __syncthreads();
  for (int k = t; k < NB; k += 256){
    int c = bh[k];
    bb2[k] = c ? atomicAdd(&gwp[k], c) : 0;
    bh[k] = 0;
  }
  __syncthreads();
  for (int e = e0 + t; e < e1; e += 256){
    int src = ei[(size_t)e * stride];
    int dst = ei[doff + (size_t)e * stride];
    int b = dst / NPB;
    int dl = dst - b * NPB;
    int idx = atomicAdd(&bh[b], 1);
    pairs[bb2[b] + idx] = src | (dl << 20);
  }
}

// ---- per-bucket CSR finalize: local degree count (== global degree), scan,
//      LDS-staged scatter, coalesced flush. Emits rowptr + dinv.
__global__ __launch_bounds__(256) void k_bucket(const int* __restrict__ pairs, const int* __restrict__ bbase,
                                                int* __restrict__ rowptr, float* __restrict__ dinv,
                                                int* __restrict__ ssrc, int NPB, int n, int Etot){
  __shared__ int lcnt[128];
  __shared__ int lexcl[129];
  __shared__ int stage[CAP];
  int b = blockIdx.x;
  int t = threadIdx.x;
  int node0 = b * NPB;
  int ebase = bbase[b], eend = bbase[b + 1];
  int cntE = eend - ebase;
  if (t <= NPB) lcnt[t] = 0;
  __syncthreads();
  for (int k = t; k < cntE; k += 256){
    unsigned int v = (unsigned int)pairs[ebase + k];
    atomicAdd(&lcnt[v >> 20], 1);
  }
  __syncthreads();
  if (t == 0){
    int s = 0;
    for (int k = 0; k < NPB; ++k){ lexcl[k] = s; s += lcnt[k]; }
    lexcl[NPB] = s;
  }
  __syncthreads();
  if (t < NPB){
    int node = node0 + t;
    if (node < n){
      rowptr[node] = ebase + lexcl[t];
      dinv[node] = rsqrtf((float)(lcnt[t] + 1));           // +1 self loop
    }
    lcnt[t] = lexcl[t];                                    // reuse as write ptr
  }
  if (b == 0 && t == 0) rowptr[n] = Etot;
  __syncthreads();
  for (int k = t; k < cntE; k += 256){
    unsigned int v = (unsigned int)pairs[ebase + k];
    int idx = atomicAdd(&lcnt[v >> 20], 1);
    int src = (int)(v & 0xFFFFFu);
    if (idx < CAP) stage[idx] = src;
    else ssrc[ebase + idx] = src;
  }
  __syncthreads();
  int m = cntE < CAP ? cntE : CAP;
  for (int k = t; k < m; k += 256) ssrc[ebase + k] = stage[k];
}

// ---- hs1 = dinv * (x @ W1), stored bf16 [N][16]. one thread per row.
__global__ __launch_bounds__(256) void k_gemm1(const float* __restrict__ x, const float* __restrict__ W1,
                                               const float* __restrict__ dinv, unsigned short* __restrict__ hs1,
                                               int n){
  int r = blockIdx.x * blockDim.x + threadIdx.x;
  if (r >= n) return;
  const float4* xr = (const float4*)(x + (size_t)r * F_IN);
  float acc[HDIM];
  #pragma unroll
  for (int j = 0; j < HDIM; ++j) acc[j] = 0.f;
  for (int k4 = 0; k4 < F_IN / 4; ++k4){
    float4 v = xr[k4];
    const float* w = W1 + k4 * 4 * HDIM;                   // uniform -> s_load
    #pragma unroll
    for (int j = 0; j < HDIM; ++j) acc[j] = fmaf(v.x, w[j], acc[j]);
    #pragma unroll
    for (int j = 0; j < HDIM; ++j) acc[j] = fmaf(v.y, w[HDIM + j], acc[j]);
    #pragma unroll
    for (int j = 0; j < HDIM; ++j) acc[j] = fmaf(v.z, w[2 * HDIM + j], acc[j]);
    #pragma unroll
    for (int j = 0; j < HDIM; ++j) acc[j] = fmaf(v.w, w[3 * HDIM + j], acc[j]);
  }
  float dv = dinv[r];
  unsigned short o[HDIM];
  #pragma unroll
  for (int j = 0; j < HDIM; ++j) o[j] = f2bf(dv * acc[j]);
  uint4 v0, v1;
  __builtin_memcpy(&v0, o, 16);
  __builtin_memcpy(&v1, o + 8, 16);
  uint4* dst = (uint4*)(hs1 + (size_t)r * HDIM);
  dst[0] = v0; dst[1] = v1;
}

// ---- conv1 aggregate + b1 + relu + @W2 + dinv scale -> hs2 bf16 [N][8]
__global__ __launch_bounds__(256) void k_agg1(const unsigned short* __restrict__ hs1,
    const int* __restrict__ rowptr, const int* __restrict__ ssrc,
    const float* __restrict__ dinv, const float* __restrict__ b1,
    const float* __restrict__ W2, unsigned short* __restrict__ hs2, int n){
  int lane = threadIdx.x & 63;
  int i = blockIdx.x * 4 + (threadIdx.x >> 6);
  if (i >= n) return;
  int s = lane >> 4, j = lane & 15;
  int beg = rowptr[i], end = rowptr[i + 1];
  float acc = 0.f;
  for (int e = beg + s; e < end; e += 4){
    int src = ssrc[e];
    acc += bf2f(hs1[(size_t)src * HDIM + j]);
  }
  acc += __shfl_xor(acc, 16);
  acc += __shfl_xor(acc, 32);
  float dv = dinv[i];
  float r = fmaxf(fmaf(dv, acc + bf2f(hs1[(size_t)i * HDIM + j]), b1[j]), 0.f);
  float p0 = r * W2[j * CDIM + 0], p1 = r * W2[j * CDIM + 1], p2 = r * W2[j * CDIM + 2];
  float p3 = r * W2[j * CDIM + 3], p4 = r * W2[j * CDIM + 4];
  #pragma unroll
  for (int off = 1; off < 16; off <<= 1){
    p0 += __shfl_xor(p0, off); p1 += __shfl_xor(p1, off); p2 += __shfl_xor(p2, off);
    p3 += __shfl_xor(p3, off); p4 += __shfl_xor(p4, off);
  }
  if (lane == 0){
    unsigned short o[8];
    o[0] = f2bf(dv * p0); o[1] = f2bf(dv * p1); o[2] = f2bf(dv * p2);
    o[3] = f2bf(dv * p3); o[4] = f2bf(dv * p4);
    o[5] = 0; o[6] = 0; o[7] = 0;
    uint4 v; __builtin_memcpy(&v, o, 16);
    *(uint4*)(hs2 + (size_t)i * 8) = v;
  }
}

// ---- conv2 aggregate + b2 + mlp + log_softmax -> out [N][5] f32
__global__ __launch_bounds__(256) void k_agg2(const unsigned short* __restrict__ hs2,
    const int* __restrict__ rowptr, const int* __restrict__ ssrc,
    const float* __restrict__ dinv, const float* __restrict__ b2,
    const float* __restrict__ W3, const float* __restrict__ b3,
    const float* __restrict__ W4, const float* __restrict__ b4,
    float* __restrict__ out, int n){
  int lane = threadIdx.x & 63;
  int i = blockIdx.x * 4 + (threadIdx.x >> 6);
  if (i >= n) return;
  int t = lane >> 3, j = lane & 7;
  int beg = rowptr[i], end = rowptr[i + 1];
  float acc = 0.f;
  for (int e = beg + t; e < end; e += 8){
    int src = ssrc[e];
    acc += bf2f(hs2[(size_t)src * 8 + j]);
  }
  acc += __shfl_xor(acc, 8);
  acc += __shfl_xor(acc, 16);
  acc += __shfl_xor(acc, 32);
  float dv = dinv[i];
  float a2 = dv * (acc + bf2f(hs2[(size_t)i * 8 + j])) + ((j < CDIM) ? b2[j] : 0.f);
  float a0 = __shfl(a2, 0), a1 = __shfl(a2, 1), a2b = __shfl(a2, 2), a3 = __shfl(a2, 3), a4 = __shfl(a2, 4);
  int m = lane & 31;
  float h3 = b3[m];
  h3 = fmaf(a0, W3[0 * 32 + m], h3);
  h3 = fmaf(a1, W3[1 * 32 + m], h3);
  h3 = fmaf(a2b, W3[2 * 32 + m], h3);
  h3 = fmaf(a3, W3[3 * 32 + m], h3);
  h3 = fmaf(a4, W3[4 * 32 + m], h3);
  h3 = fmaxf(h3, 0.f);
  float q0 = h3 * W4[m * CDIM + 0], q1 = h3 * W4[m * CDIM + 1], q2 = h3 * W4[m * CDIM + 2];
  float q3 = h3 * W4[m * CDIM + 3], q4 = h3 * W4[m * CDIM + 4];
  #pragma unroll
  for (int off = 1; off < 32; off <<= 1){
    q0 += __shfl_xor(q0, off); q1 += __shfl_xor(q1, off); q2 += __shfl_xor(q2, off);
    q3 += __shfl_xor(q3, off); q4 += __shfl_xor(q4, off);
  }
  q0 += b4[0]; q1 += b4[1]; q2 += b4[2]; q3 += b4[3]; q4 += b4[4];
  float mx = fmaxf(fmaxf(fmaxf(q0, q1), fmaxf(q2, q3)), q4);
  float sum = expf(q0 - mx) + expf(q1 - mx) + expf(q2 - mx) + expf(q3 - mx) + expf(q4 - mx);
  float lse = mx + logf(sum);
  if (lane < CDIM){
    float v = q0;
    if (lane == 1) v = q1;
    if (lane == 2) v = q2;
    if (lane == 3) v = q3;
    if (lane == 4) v = q4;
    out[(size_t)i * CDIM + lane] = v - lse;
  }
}

extern "C" void kernel_launch(void* const* d_in, const int* in_sizes, int n_in,
                              void* d_out, int out_size, void* d_ws, size_t ws_size,
                              hipStream_t stream){
  const float* x  = (const float*)d_in[0];
  const int*   ei = (const int*)d_in[1];
  const float* W1 = (const float*)d_in[2];
  const float* b1 = (const float*)d_in[3];
  const float* W2 = (const float*)d_in[4];
  const float* b2 = (const float*)d_in[5];
  const float* W3 = (const float*)d_in[6];
  const float* b3 = (const float*)d_in[7];
  const float* W4 = (const float*)d_in[8];
  const float* b4 = (const float*)d_in[9];
  float* out = (float*)d_out;

  int N = in_sizes[0] / F_IN;
  int E = in_sizes[1] / 2;
  int NPB = (N + NB - 1) / NB;      // nodes per bucket (98 for N=100000)

  char* ws = (char*)d_ws;
  size_t off = 0;
  auto alloc = [&](size_t bytes) -> char* {
    char* p = ws + off;
    off += (bytes + 255) & ~(size_t)255;
    return p;
  };
  int* bhist = (int*)alloc(((size_t)NB + 1) * 4);  // flag at bhist[NB]
  int* flag  = bhist + NB;
  int* bbase = (int*)alloc(((size_t)NB + 1) * 4);
  int* gwp   = (int*)alloc((size_t)NB * 4);
  int* rowptr= (int*)alloc(((size_t)N + 1) * 4);
  float* dinv= (float*)alloc((size_t)N * 4);
  int* pairs = (int*)alloc((size_t)E * 4);
  int* ssrc  = (int*)alloc((size_t)E * 4);
  unsigned short* hs1 = (unsigned short*)alloc((size_t)N * HDIM * 2);
  unsigned short* hs2 = (unsigned short*)alloc((size_t)N * 8 * 2);
  (void)ws_size; (void)n_in; (void)out_size;

  hipMemsetAsync(bhist, 0, ((size_t)NB + 1) * 4, stream);
  k_detect<<<8, 256, 0, stream>>>(ei, flag, E);
  k_binhist<<<1024, 256, 0, stream>>>(ei, flag, bhist, E, NPB);
  k_scanNB<<<1, 1024, 0, stream>>>(bhist, bbase, gwp, NB);
  k_binscatter<<<SCAT_BLOCKS, 256, 0, stream>>>(ei, flag, gwp, pairs, E, NPB);
  k_bucket<<<NB, 256, 0, stream>>>(pairs, bbase, rowptr, dinv, ssrc, NPB, N, E);
  k_gemm1<<<(N + 255) / 256, 256, 0, stream>>>(x, W1, dinv, hs1, N);
  k_agg1<<<(N + 3) / 4, 256, 0, stream>>>(hs1, rowptr, ssrc, dinv, b1, W2, hs2, N);
  k_agg2<<<(N + 3) / 4, 256, 0, stream>>>(hs2, rowptr, ssrc, dinv, b2, W3, b3, W4, b4, out, N);
}

// Round 3
// 455.577 us; speedup vs baseline: 2.7465x; 1.1664x over previous
//
#include <hip/hip_runtime.h>
#include <hip/hip_bf16.h>

// GCN: conv1(512->16) + relu + conv2(16->5) + mlp(5->32->5) + log_softmax
// out[dst] = dinv[dst]*(sum_{src in N(dst)} hs[src] + hs[dst]) + b,  hs = dinv*(h@W)
// CSR build via 2-level binning (1024 dst-range buckets) to avoid random 4B scatter.

#define F_IN 512
#define HDIM 16
#define CDIM 5
#define NB   1024      // dst-range buckets
#define SCAT_BLOCKS 512
#define SCAT_THREADS 1024
#define CAP  8192      // per-bucket LDS staging (ints); fallback to direct store if exceeded

__device__ inline float bf2f(unsigned short u){
  unsigned int i = ((unsigned int)u) << 16; float f; __builtin_memcpy(&f, &i, 4); return f;
}
__device__ inline unsigned short f2bf(float x){
  unsigned int i; __builtin_memcpy(&i, &x, 4);
  unsigned int r = i + 0x7FFFu + ((i >> 16) & 1u);
  return (unsigned short)(r >> 16);
}

// ---- detect int64 vs int32 edge_index layout: odd 32-bit words all zero => int64
__global__ void k_detect(const int* __restrict__ ei, int* __restrict__ flag, int E){
  int k = blockIdx.x * blockDim.x + threadIdx.x;
  long long step = E / 2048; if (step < 1) step = 1;
  long long pos = 2LL * ((long long)k * step) + 1;
  if (pos < 2LL * E){
    if (ei[pos] != 0) atomicOr(flag, 1);                   // nonzero odd word => int32
  }
}

// ---- per-bucket histogram (LDS-staged)
__global__ __launch_bounds__(256) void k_binhist(const int* __restrict__ ei, const int* __restrict__ flag,
                                                 int* __restrict__ bhist, int E, int NPB){
  __shared__ int h[NB];
  for (int k = threadIdx.x; k < NB; k += 256) h[k] = 0;
  __syncthreads();
  int is32 = *flag;
  int stride = is32 ? 1 : 2;
  size_t doff = is32 ? (size_t)E : (size_t)2 * E;
  for (long long e = blockIdx.x * blockDim.x + threadIdx.x; e < E;
       e += (long long)gridDim.x * blockDim.x){
    int dst = ei[doff + (size_t)e * stride];
    atomicAdd(&h[dst / NPB], 1);
  }
  __syncthreads();
  for (int k = threadIdx.x; k < NB; k += 256){
    int v = h[k];
    if (v) atomicAdd(&bhist[k], v);
  }
}

// ---- exclusive scan over NB buckets -> bbase, gwp
__global__ __launch_bounds__(1024) void k_scanNB(const int* __restrict__ cnt, int* __restrict__ bbase,
                                                 int* __restrict__ gwp, int nb){
  __shared__ int wsum[16];
  __shared__ int carry_s;
  int t = threadIdx.x, lane = t & 63, w = t >> 6;
  if (t == 0) carry_s = 0;
  __syncthreads();
  for (int base = 0; base < nb; base += 1024){
    int i = base + t;
    int v = (i < nb) ? cnt[i] : 0;
    int xs = v;
    #pragma unroll
    for (int off = 1; off < 64; off <<= 1){
      int y = __shfl_up(xs, off);
      if (lane >= off) xs += y;
    }
    if (lane == 63) wsum[w] = xs;
    __syncthreads();
    int woff = 0;
    for (int k = 0; k < w; ++k) woff += wsum[k];
    int carry = carry_s;
    if (i < nb){
      int excl = carry + woff + xs - v;
      bbase[i] = excl; gwp[i] = excl;
    }
    __syncthreads();
    if (t == 1023) carry_s = carry + woff + xs;
    __syncthreads();
  }
  if (t == 0) bbase[nb] = carry_s;
}

// ---- chunked scatter: each block reserves per-bucket runs, writes packed src|dl<<20
__global__ __launch_bounds__(SCAT_THREADS) void k_binscatter(const int* __restrict__ ei, const int* __restrict__ flag,
                                                    int* __restrict__ gwp, int* __restrict__ pairs,
                                                    int E, int NPB){
  __shared__ int bh[NB];
  __shared__ int bb2[NB];
  int t = threadIdx.x;
  int chunk = (E + gridDim.x - 1) / gridDim.x;
  int e0 = blockIdx.x * chunk;
  int e1 = min(E, e0 + chunk);
  int is32 = *flag;
  int stride = is32 ? 1 : 2;
  size_t doff = is32 ? (size_t)E : (size_t)2 * E;
  for (int k = t; k < NB; k += SCAT_THREADS) bh[k] = 0;
  __syncthreads();
  for (int e = e0 + t; e < e1; e += SCAT_THREADS){
    int dst = ei[doff + (size_t)e * stride];
    atomicAdd(&bh[dst / NPB], 1);
  }
  __syncthreads();
  for (int k = t; k < NB; k += SCAT_THREADS){
    int c = bh[k];
    bb2[k] = c ? atomicAdd(&gwp[k], c) : 0;
    bh[k] = 0;
  }
  __syncthreads();
  for (int e = e0 + t; e < e1; e += SCAT_THREADS){
    int src = ei[(size_t)e * stride];
    int dst = ei[doff + (size_t)e * stride];
    int b = dst / NPB;
    int dl = dst - b * NPB;
    int idx = atomicAdd(&bh[b], 1);
    pairs[bb2[b] + idx] = src | (dl << 20);
  }
}

// ---- per-bucket CSR finalize: local degree count (== global degree), scan,
//      LDS-staged scatter, coalesced flush. Emits rowptr + dinv.
__global__ __launch_bounds__(256) void k_bucket(const int* __restrict__ pairs, const int* __restrict__ bbase,
                                                int* __restrict__ rowptr, float* __restrict__ dinv,
                                                int* __restrict__ ssrc, int NPB, int n, int Etot){
  __shared__ int lcnt[128];
  __shared__ int lexcl[129];
  __shared__ int stage[CAP];
  int b = blockIdx.x;
  int t = threadIdx.x;
  int node0 = b * NPB;
  int ebase = bbase[b], eend = bbase[b + 1];
  int cntE = eend - ebase;
  if (t <= NPB) lcnt[t] = 0;
  __syncthreads();
  for (int k = t; k < cntE; k += 256){
    unsigned int v = (unsigned int)pairs[ebase + k];
    atomicAdd(&lcnt[v >> 20], 1);
  }
  __syncthreads();
  if (t == 0){
    int s = 0;
    for (int k = 0; k < NPB; ++k){ lexcl[k] = s; s += lcnt[k]; }
    lexcl[NPB] = s;
  }
  __syncthreads();
  if (t < NPB){
    int node = node0 + t;
    if (node < n){
      rowptr[node] = ebase + lexcl[t];
      dinv[node] = rsqrtf((float)(lcnt[t] + 1));           // +1 self loop
    }
    lcnt[t] = lexcl[t];                                    // reuse as write ptr
  }
  if (b == 0 && t == 0) rowptr[n] = Etot;
  __syncthreads();
  for (int k = t; k < cntE; k += 256){
    unsigned int v = (unsigned int)pairs[ebase + k];
    int idx = atomicAdd(&lcnt[v >> 20], 1);
    int src = (int)(v & 0xFFFFFu);
    if (idx < CAP) stage[idx] = src;
    else ssrc[ebase + idx] = src;
  }
  __syncthreads();
  int m = cntE < CAP ? cntE : CAP;
  for (int k = t; k < m; k += 256) ssrc[ebase + k] = stage[k];
}

// ---- hs1 = dinv * (x @ W1), stored bf16 [N][16]. one thread per row.
__global__ __launch_bounds__(256) void k_gemm1(const float* __restrict__ x, const float* __restrict__ W1,
                                               const float* __restrict__ dinv, unsigned short* __restrict__ hs1,
                                               int n){
  int r = blockIdx.x * blockDim.x + threadIdx.x;
  if (r >= n) return;
  const float4* xr = (const float4*)(x + (size_t)r * F_IN);
  float acc[HDIM];
  #pragma unroll
  for (int j = 0; j < HDIM; ++j) acc[j] = 0.f;
  for (int k4 = 0; k4 < F_IN / 4; ++k4){
    float4 v = xr[k4];
    const float* w = W1 + k4 * 4 * HDIM;                   // uniform -> s_load
    #pragma unroll
    for (int j = 0; j < HDIM; ++j) acc[j] = fmaf(v.x, w[j], acc[j]);
    #pragma unroll
    for (int j = 0; j < HDIM; ++j) acc[j] = fmaf(v.y, w[HDIM + j], acc[j]);
    #pragma unroll
    for (int j = 0; j < HDIM; ++j) acc[j] = fmaf(v.z, w[2 * HDIM + j], acc[j]);
    #pragma unroll
    for (int j = 0; j < HDIM; ++j) acc[j] = fmaf(v.w, w[3 * HDIM + j], acc[j]);
  }
  float dv = dinv[r];
  unsigned short o[HDIM];
  #pragma unroll
  for (int j = 0; j < HDIM; ++j) o[j] = f2bf(dv * acc[j]);
  uint4 v0, v1;
  __builtin_memcpy(&v0, o, 16);
  __builtin_memcpy(&v1, o + 8, 16);
  uint4* dst = (uint4*)(hs1 + (size_t)r * HDIM);
  dst[0] = v0; dst[1] = v1;
}

// ---- conv1 aggregate + b1 + relu + @W2 + dinv scale -> hs2 bf16 [N][8]
__global__ __launch_bounds__(256) void k_agg1(const unsigned short* __restrict__ hs1,
    const int* __restrict__ rowptr, const int* __restrict__ ssrc,
    const float* __restrict__ dinv, const float* __restrict__ b1,
    const float* __restrict__ W2, unsigned short* __restrict__ hs2, int n){
  int lane = threadIdx.x & 63;
  int i = blockIdx.x * 4 + (threadIdx.x >> 6);
  if (i >= n) return;
  int s = lane >> 4, j = lane & 15;
  int beg = rowptr[i], end = rowptr[i + 1];
  float acc = 0.f;
  for (int e = beg + s; e < end; e += 4){
    int src = ssrc[e];
    acc += bf2f(hs1[(size_t)src * HDIM + j]);
  }
  acc += __shfl_xor(acc, 16);
  acc += __shfl_xor(acc, 32);
  float dv = dinv[i];
  float r = fmaxf(fmaf(dv, acc + bf2f(hs1[(size_t)i * HDIM + j]), b1[j]), 0.f);
  float p0 = r * W2[j * CDIM + 0], p1 = r * W2[j * CDIM + 1], p2 = r * W2[j * CDIM + 2];
  float p3 = r * W2[j * CDIM + 3], p4 = r * W2[j * CDIM + 4];
  #pragma unroll
  for (int off = 1; off < 16; off <<= 1){
    p0 += __shfl_xor(p0, off); p1 += __shfl_xor(p1, off); p2 += __shfl_xor(p2, off);
    p3 += __shfl_xor(p3, off); p4 += __shfl_xor(p4, off);
  }
  if (lane == 0){
    unsigned short o[8];
    o[0] = f2bf(dv * p0); o[1] = f2bf(dv * p1); o[2] = f2bf(dv * p2);
    o[3] = f2bf(dv * p3); o[4] = f2bf(dv * p4);
    o[5] = 0; o[6] = 0; o[7] = 0;
    uint4 v; __builtin_memcpy(&v, o, 16);
    *(uint4*)(hs2 + (size_t)i * 8) = v;
  }
}

// ---- conv2 aggregate + b2 + mlp + log_softmax -> out [N][5] f32
__global__ __launch_bounds__(256) void k_agg2(const unsigned short* __restrict__ hs2,
    const int* __restrict__ rowptr, const int* __restrict__ ssrc,
    const float* __restrict__ dinv, const float* __restrict__ b2,
    const float* __restrict__ W3, const float* __restrict__ b3,
    const float* __restrict__ W4, const float* __restrict__ b4,
    float* __restrict__ out, int n){
  int lane = threadIdx.x & 63;
  int i = blockIdx.x * 4 + (threadIdx.x >> 6);
  if (i >= n) return;
  int t = lane >> 3, j = lane & 7;
  int beg = rowptr[i], end = rowptr[i + 1];
  float acc = 0.f;
  for (int e = beg + t; e < end; e += 8){
    int src = ssrc[e];
    acc += bf2f(hs2[(size_t)src * 8 + j]);
  }
  acc += __shfl_xor(acc, 8);
  acc += __shfl_xor(acc, 16);
  acc += __shfl_xor(acc, 32);
  float dv = dinv[i];
  float a2 = dv * (acc + bf2f(hs2[(size_t)i * 8 + j])) + ((j < CDIM) ? b2[j] : 0.f);
  float a0 = __shfl(a2, 0), a1 = __shfl(a2, 1), a2b = __shfl(a2, 2), a3 = __shfl(a2, 3), a4 = __shfl(a2, 4);
  int m = lane & 31;
  float h3 = b3[m];
  h3 = fmaf(a0, W3[0 * 32 + m], h3);
  h3 = fmaf(a1, W3[1 * 32 + m], h3);
  h3 = fmaf(a2b, W3[2 * 32 + m], h3);
  h3 = fmaf(a3, W3[3 * 32 + m], h3);
  h3 = fmaf(a4, W3[4 * 32 + m], h3);
  h3 = fmaxf(h3, 0.f);
  float q0 = h3 * W4[m * CDIM + 0], q1 = h3 * W4[m * CDIM + 1], q2 = h3 * W4[m * CDIM + 2];
  float q3 = h3 * W4[m * CDIM + 3], q4 = h3 * W4[m * CDIM + 4];
  #pragma unroll
  for (int off = 1; off < 32; off <<= 1){
    q0 += __shfl_xor(q0, off); q1 += __shfl_xor(q1, off); q2 += __shfl_xor(q2, off);
    q3 += __shfl_xor(q3, off); q4 += __shfl_xor(q4, off);
  }
  q0 += b4[0]; q1 += b4[1]; q2 += b4[2]; q3 += b4[3]; q4 += b4[4];
  float mx = fmaxf(fmaxf(fmaxf(q0, q1), fmaxf(q2, q3)), q4);
  float sum = expf(q0 - mx) + expf(q1 - mx) + expf(q2 - mx) + expf(q3 - mx) + expf(q4 - mx);
  float lse = mx + logf(sum);
  if (lane < CDIM){
    float v = q0;
    if (lane == 1) v = q1;
    if (lane == 2) v = q2;
    if (lane == 3) v = q3;
    if (lane == 4) v = q4;
    out[(size_t)i * CDIM + lane] = v - lse;
  }
}

extern "C" void kernel_launch(void* const* d_in, const int* in_sizes, int n_in,
                              void* d_out, int out_size, void* d_ws, size_t ws_size,
                              hipStream_t stream){
  const float* x  = (const float*)d_in[0];
  const int*   ei = (const int*)d_in[1];
  const float* W1 = (const float*)d_in[2];
  const float* b1 = (const float*)d_in[3];
  const float* W2 = (const float*)d_in[4];
  const float* b2 = (const float*)d_in[5];
  const float* W3 = (const float*)d_in[6];
  const float* b3 = (const float*)d_in[7];
  const float* W4 = (const float*)d_in[8];
  const float* b4 = (const float*)d_in[9];
  float* out = (float*)d_out;

  int N = in_sizes[0] / F_IN;
  int E = in_sizes[1] / 2;
  int NPB = (N + NB - 1) / NB;      // nodes per bucket (98 for N=100000)

  char* ws = (char*)d_ws;
  size_t off = 0;
  auto alloc = [&](size_t bytes) -> char* {
    char* p = ws + off;
    off += (bytes + 255) & ~(size_t)255;
    return p;
  };
  int* bhist = (int*)alloc(((size_t)NB + 1) * 4);  // flag at bhist[NB]
  int* flag  = bhist + NB;
  int* bbase = (int*)alloc(((size_t)NB + 1) * 4);
  int* gwp   = (int*)alloc((size_t)NB * 4);
  int* rowptr= (int*)alloc(((size_t)N + 1) * 4);
  float* dinv= (float*)alloc((size_t)N * 4);
  int* pairs = (int*)alloc((size_t)E * 4);
  int* ssrc  = (int*)alloc((size_t)E * 4);
  unsigned short* hs1 = (unsigned short*)alloc((size_t)N * HDIM * 2);
  unsigned short* hs2 = (unsigned short*)alloc((size_t)N * 8 * 2);
  (void)ws_size; (void)n_in; (void)out_size;

  hipMemsetAsync(bhist, 0, ((size_t)NB + 1) * 4, stream);
  k_detect<<<8, 256, 0, stream>>>(ei, flag, E);
  k_binhist<<<2048, 256, 0, stream>>>(ei, flag, bhist, E, NPB);
  k_scanNB<<<1, 1024, 0, stream>>>(bhist, bbase, gwp, NB);
  k_binscatter<<<SCAT_BLOCKS, SCAT_THREADS, 0, stream>>>(ei, flag, gwp, pairs, E, NPB);
  k_bucket<<<NB, 256, 0, stream>>>(pairs, bbase, rowptr, dinv, ssrc, NPB, N, E);
  k_gemm1<<<(N + 255) / 256, 256, 0, stream>>>(x, W1, dinv, hs1, N);
  k_agg1<<<(N + 3) / 4, 256, 0, stream>>>(hs1, rowptr, ssrc, dinv, b1, W2, hs2, N);
  k_agg2<<<(N + 3) / 4, 256, 0, stream>>>(hs2, rowptr, ssrc, dinv, b2, W3, b3, W4, b4, out, N);
}

// Round 4
// 395.410 us; speedup vs baseline: 3.1644x; 1.1522x over previous
//
#include <hip/hip_runtime.h>
#include <hip/hip_bf16.h>

// GCN: conv1(512->16) + relu + conv2(16->5) + mlp(5->32->5) + log_softmax
// out[dst] = dinv[dst]*(sum_{src in N(dst)} hs[src] + hs[dst]) + b,  hs = dinv*(h@W)
// CSR build via 2-level binning (1024 dst-range buckets) to avoid random 4B scatter.
// agg kernels: wave per node, wide (16B/lane) gathers for max edge-parallelism.

#define F_IN 512
#define HDIM 16
#define CDIM 5
#define NB   1024      // dst-range buckets
#define SCAT_BLOCKS 512
#define SCAT_THREADS 1024
#define CAP  8192      // per-bucket LDS staging (ints)

__device__ inline float bf2f(unsigned short u){
  unsigned int i = ((unsigned int)u) << 16; float f; __builtin_memcpy(&f, &i, 4); return f;
}
__device__ inline unsigned short f2bf(float x){
  unsigned int i; __builtin_memcpy(&i, &x, 4);
  unsigned int r = i + 0x7FFFu + ((i >> 16) & 1u);
  return (unsigned short)(r >> 16);
}
__device__ inline float ulo(unsigned int u){   // low bf16 of a packed word -> f32
  unsigned int v = u << 16; float f; __builtin_memcpy(&f, &v, 4); return f;
}
__device__ inline float uhi(unsigned int u){   // high bf16 of a packed word -> f32
  unsigned int v = u & 0xFFFF0000u; float f; __builtin_memcpy(&f, &v, 4); return f;
}

// ---- detect int64 vs int32 edge_index layout: odd 32-bit words all zero => int64
__global__ void k_detect(const int* __restrict__ ei, int* __restrict__ flag, int E){
  int k = blockIdx.x * blockDim.x + threadIdx.x;
  long long step = E / 2048; if (step < 1) step = 1;
  long long pos = 2LL * ((long long)k * step) + 1;
  if (pos < 2LL * E){
    if (ei[pos] != 0) atomicOr(flag, 1);                   // nonzero odd word => int32
  }
}

// ---- per-bucket histogram (LDS-staged)
__global__ __launch_bounds__(256) void k_binhist(const int* __restrict__ ei, const int* __restrict__ flag,
                                                 int* __restrict__ bhist, int E, int NPB){
  __shared__ int h[NB];
  for (int k = threadIdx.x; k < NB; k += 256) h[k] = 0;
  __syncthreads();
  int is32 = *flag;
  int stride = is32 ? 1 : 2;
  size_t doff = is32 ? (size_t)E : (size_t)2 * E;
  for (long long e = blockIdx.x * blockDim.x + threadIdx.x; e < E;
       e += (long long)gridDim.x * blockDim.x){
    int dst = ei[doff + (size_t)e * stride];
    atomicAdd(&h[dst / NPB], 1);
  }
  __syncthreads();
  for (int k = threadIdx.x; k < NB; k += 256){
    int v = h[k];
    if (v) atomicAdd(&bhist[k], v);
  }
}

// ---- exclusive scan over NB buckets -> bbase, gwp
__global__ __launch_bounds__(1024) void k_scanNB(const int* __restrict__ cnt, int* __restrict__ bbase,
                                                 int* __restrict__ gwp, int nb){
  __shared__ int wsum[16];
  __shared__ int carry_s;
  int t = threadIdx.x, lane = t & 63, w = t >> 6;
  if (t == 0) carry_s = 0;
  __syncthreads();
  for (int base = 0; base < nb; base += 1024){
    int i = base + t;
    int v = (i < nb) ? cnt[i] : 0;
    int xs = v;
    #pragma unroll
    for (int off = 1; off < 64; off <<= 1){
      int y = __shfl_up(xs, off);
      if (lane >= off) xs += y;
    }
    if (lane == 63) wsum[w] = xs;
    __syncthreads();
    int woff = 0;
    for (int k = 0; k < w; ++k) woff += wsum[k];
    int carry = carry_s;
    if (i < nb){
      int excl = carry + woff + xs - v;
      bbase[i] = excl; gwp[i] = excl;
    }
    __syncthreads();
    if (t == 1023) carry_s = carry + woff + xs;
    __syncthreads();
  }
  if (t == 0) bbase[nb] = carry_s;
}

// ---- chunked scatter: each block reserves per-bucket runs, writes packed src|dl<<20
__global__ __launch_bounds__(SCAT_THREADS) void k_binscatter(const int* __restrict__ ei, const int* __restrict__ flag,
                                                    int* __restrict__ gwp, int* __restrict__ pairs,
                                                    int E, int NPB){
  __shared__ int bh[NB];
  __shared__ int bb2[NB];
  int t = threadIdx.x;
  int chunk = (E + gridDim.x - 1) / gridDim.x;
  int e0 = blockIdx.x * chunk;
  int e1 = min(E, e0 + chunk);
  int is32 = *flag;
  int stride = is32 ? 1 : 2;
  size_t doff = is32 ? (size_t)E : (size_t)2 * E;
  for (int k = t; k < NB; k += SCAT_THREADS) bh[k] = 0;
  __syncthreads();
  for (int e = e0 + t; e < e1; e += SCAT_THREADS){
    int dst = ei[doff + (size_t)e * stride];
    atomicAdd(&bh[dst / NPB], 1);
  }
  __syncthreads();
  for (int k = t; k < NB; k += SCAT_THREADS){
    int c = bh[k];
    bb2[k] = c ? atomicAdd(&gwp[k], c) : 0;
    bh[k] = 0;
  }
  __syncthreads();
  for (int e = e0 + t; e < e1; e += SCAT_THREADS){
    int src = ei[(size_t)e * stride];
    int dst = ei[doff + (size_t)e * stride];
    int b = dst / NPB;
    int dl = dst - b * NPB;
    int idx = atomicAdd(&bh[b], 1);
    pairs[bb2[b] + idx] = src | (dl << 20);
  }
}

// ---- per-bucket CSR finalize
__global__ __launch_bounds__(256) void k_bucket(const int* __restrict__ pairs, const int* __restrict__ bbase,
                                                int* __restrict__ rowptr, float* __restrict__ dinv,
                                                int* __restrict__ ssrc, int NPB, int n, int Etot){
  __shared__ int lcnt[128];
  __shared__ int lexcl[129];
  __shared__ int stage[CAP];
  int b = blockIdx.x;
  int t = threadIdx.x;
  int node0 = b * NPB;
  int ebase = bbase[b], eend = bbase[b + 1];
  int cntE = eend - ebase;
  if (t <= NPB) lcnt[t] = 0;
  __syncthreads();
  for (int k = t; k < cntE; k += 256){
    unsigned int v = (unsigned int)pairs[ebase + k];
    atomicAdd(&lcnt[v >> 20], 1);
  }
  __syncthreads();
  if (t == 0){
    int s = 0;
    for (int k = 0; k < NPB; ++k){ lexcl[k] = s; s += lcnt[k]; }
    lexcl[NPB] = s;
  }
  __syncthreads();
  if (t < NPB){
    int node = node0 + t;
    if (node < n){
      rowptr[node] = ebase + lexcl[t];
      dinv[node] = rsqrtf((float)(lcnt[t] + 1));           // +1 self loop
    }
    lcnt[t] = lexcl[t];                                    // reuse as write ptr
  }
  if (b == 0 && t == 0) rowptr[n] = Etot;
  __syncthreads();
  for (int k = t; k < cntE; k += 256){
    unsigned int v = (unsigned int)pairs[ebase + k];
    int idx = atomicAdd(&lcnt[v >> 20], 1);
    int src = (int)(v & 0xFFFFFu);
    if (idx < CAP) stage[idx] = src;
    else ssrc[ebase + idx] = src;
  }
  __syncthreads();
  int m = cntE < CAP ? cntE : CAP;
  for (int k = t; k < m; k += 256) ssrc[ebase + k] = stage[k];
}

// ---- hs1 = dinv * (x @ W1), stored bf16 [N][16]. one thread per row.
__global__ __launch_bounds__(256) void k_gemm1(const float* __restrict__ x, const float* __restrict__ W1,
                                               const float* __restrict__ dinv, unsigned short* __restrict__ hs1,
                                               int n){
  int r = blockIdx.x * blockDim.x + threadIdx.x;
  if (r >= n) return;
  const float4* xr = (const float4*)(x + (size_t)r * F_IN);
  float acc[HDIM];
  #pragma unroll
  for (int j = 0; j < HDIM; ++j) acc[j] = 0.f;
  for (int k4 = 0; k4 < F_IN / 4; ++k4){
    float4 v = xr[k4];
    const float* w = W1 + k4 * 4 * HDIM;                   // uniform -> s_load
    #pragma unroll
    for (int j = 0; j < HDIM; ++j) acc[j] = fmaf(v.x, w[j], acc[j]);
    #pragma unroll
    for (int j = 0; j < HDIM; ++j) acc[j] = fmaf(v.y, w[HDIM + j], acc[j]);
    #pragma unroll
    for (int j = 0; j < HDIM; ++j) acc[j] = fmaf(v.z, w[2 * HDIM + j], acc[j]);
    #pragma unroll
    for (int j = 0; j < HDIM; ++j) acc[j] = fmaf(v.w, w[3 * HDIM + j], acc[j]);
  }
  float dv = dinv[r];
  unsigned short o[HDIM];
  #pragma unroll
  for (int j = 0; j < HDIM; ++j) o[j] = f2bf(dv * acc[j]);
  uint4 v0, v1;
  __builtin_memcpy(&v0, o, 16);
  __builtin_memcpy(&v1, o + 8, 16);
  uint4* dst = (uint4*)(hs1 + (size_t)r * HDIM);
  dst[0] = v0; dst[1] = v1;
}

// ---- conv1 aggregate + b1 + relu + @W2 + dinv scale -> hs2 bf16 [N][8]
// wave per node; 2 lanes per edge (each lane: uint4 = 8 bf16 = half hs1 row).
__global__ __launch_bounds__(256) void k_agg1(const unsigned short* __restrict__ hs1,
    const int* __restrict__ rowptr, const int* __restrict__ ssrc,
    const float* __restrict__ dinv, const float* __restrict__ b1,
    const float* __restrict__ W2, unsigned short* __restrict__ hs2, int n){
  int lane = threadIdx.x & 63;
  int i = blockIdx.x * 4 + (threadIdx.x >> 6);
  if (i >= n) return;
  int slot = lane >> 1, half = lane & 1;
  int beg = rowptr[i], end = rowptr[i + 1];
  const uint4* hv = (const uint4*)hs1;                 // row = 2 uint4
  float acc[8];
  #pragma unroll
  for (int k = 0; k < 8; ++k) acc[k] = 0.f;
  for (int e = beg + slot; e < end; e += 32){
    int src = ssrc[e];
    uint4 v = hv[(size_t)src * 2 + half];
    acc[0] += ulo(v.x); acc[1] += uhi(v.x);
    acc[2] += ulo(v.y); acc[3] += uhi(v.y);
    acc[4] += ulo(v.z); acc[5] += uhi(v.z);
    acc[6] += ulo(v.w); acc[7] += uhi(v.w);
  }
  #pragma unroll
  for (int off = 2; off < 64; off <<= 1){
    #pragma unroll
    for (int k = 0; k < 8; ++k) acc[k] += __shfl_xor(acc[k], off);
  }
  // self term + bias + relu
  uint4 sv = hv[(size_t)i * 2 + half];
  float self[8] = {ulo(sv.x), uhi(sv.x), ulo(sv.y), uhi(sv.y),
                   ulo(sv.z), uhi(sv.z), ulo(sv.w), uhi(sv.w)};
  float dv = dinv[i];
  const float4* b1v = (const float4*)b1;
  float4 bl = b1v[half * 2], bh = b1v[half * 2 + 1];
  float r[8];
  r[0] = fmaxf(fmaf(dv, acc[0] + self[0], bl.x), 0.f);
  r[1] = fmaxf(fmaf(dv, acc[1] + self[1], bl.y), 0.f);
  r[2] = fmaxf(fmaf(dv, acc[2] + self[2], bl.z), 0.f);
  r[3] = fmaxf(fmaf(dv, acc[3] + self[3], bl.w), 0.f);
  r[4] = fmaxf(fmaf(dv, acc[4] + self[4], bh.x), 0.f);
  r[5] = fmaxf(fmaf(dv, acc[5] + self[5], bh.y), 0.f);
  r[6] = fmaxf(fmaf(dv, acc[6] + self[6], bh.z), 0.f);
  r[7] = fmaxf(fmaf(dv, acc[7] + self[7], bh.w), 0.f);
  // @W2 (each lane does its half's 8 rows), fold halves with one shfl
  const float* w2 = W2 + half * 8 * CDIM;
  float p[CDIM];
  #pragma unroll
  for (int c = 0; c < CDIM; ++c){
    float s = 0.f;
    #pragma unroll
    for (int k = 0; k < 8; ++k) s = fmaf(r[k], w2[k * CDIM + c], s);
    p[c] = s;
  }
  #pragma unroll
  for (int c = 0; c < CDIM; ++c) p[c] += __shfl_xor(p[c], 1);
  if (lane == 0){
    unsigned short o[8];
    #pragma unroll
    for (int c = 0; c < CDIM; ++c) o[c] = f2bf(dv * p[c]);
    o[5] = 0; o[6] = 0; o[7] = 0;
    uint4 v; __builtin_memcpy(&v, o, 16);
    *(uint4*)(hs2 + (size_t)i * 8) = v;
  }
}

// ---- conv2 aggregate + b2 + mlp + log_softmax -> out [N][5] f32
// wave per node; 1 lane per edge (uint4 = full hs2 row).
__global__ __launch_bounds__(256) void k_agg2(const unsigned short* __restrict__ hs2,
    const int* __restrict__ rowptr, const int* __restrict__ ssrc,
    const float* __restrict__ dinv, const float* __restrict__ b2,
    const float* __restrict__ W3, const float* __restrict__ b3,
    const float* __restrict__ W4, const float* __restrict__ b4,
    float* __restrict__ out, int n){
  int lane = threadIdx.x & 63;
  int i = blockIdx.x * 4 + (threadIdx.x >> 6);
  if (i >= n) return;
  int beg = rowptr[i], end = rowptr[i + 1];
  const uint4* hv = (const uint4*)hs2;                 // row = 1 uint4
  float acc[CDIM];
  #pragma unroll
  for (int k = 0; k < CDIM; ++k) acc[k] = 0.f;
  for (int e = beg + lane; e < end; e += 64){
    int src = ssrc[e];
    uint4 v = hv[src];
    acc[0] += ulo(v.x); acc[1] += uhi(v.x);
    acc[2] += ulo(v.y); acc[3] += uhi(v.y);
    acc[4] += ulo(v.z);
  }
  #pragma unroll
  for (int off = 1; off < 64; off <<= 1){
    #pragma unroll
    for (int k = 0; k < CDIM; ++k) acc[k] += __shfl_xor(acc[k], off);
  }
  float dv = dinv[i];
  uint4 sv = hv[i];
  float a0 = fmaf(dv, acc[0] + ulo(sv.x), b2[0]);
  float a1 = fmaf(dv, acc[1] + uhi(sv.x), b2[1]);
  float a2 = fmaf(dv, acc[2] + ulo(sv.y), b2[2]);
  float a3 = fmaf(dv, acc[3] + uhi(sv.y), b2[3]);
  float a4 = fmaf(dv, acc[4] + ulo(sv.z), b2[4]);
  int m = lane & 31;
  float h3 = b3[m];
  h3 = fmaf(a0, W3[0 * 32 + m], h3);
  h3 = fmaf(a1, W3[1 * 32 + m], h3);
  h3 = fmaf(a2, W3[2 * 32 + m], h3);
  h3 = fmaf(a3, W3[3 * 32 + m], h3);
  h3 = fmaf(a4, W3[4 * 32 + m], h3);
  h3 = fmaxf(h3, 0.f);
  float q0 = h3 * W4[m * CDIM + 0], q1 = h3 * W4[m * CDIM + 1], q2 = h3 * W4[m * CDIM + 2];
  float q3 = h3 * W4[m * CDIM + 3], q4 = h3 * W4[m * CDIM + 4];
  #pragma unroll
  for (int off = 1; off < 32; off <<= 1){
    q0 += __shfl_xor(q0, off); q1 += __shfl_xor(q1, off); q2 += __shfl_xor(q2, off);
    q3 += __shfl_xor(q3, off); q4 += __shfl_xor(q4, off);
  }
  q0 += b4[0]; q1 += b4[1]; q2 += b4[2]; q3 += b4[3]; q4 += b4[4];
  float mx = fmaxf(fmaxf(fmaxf(q0, q1), fmaxf(q2, q3)), q4);
  float sum = expf(q0 - mx) + expf(q1 - mx) + expf(q2 - mx) + expf(q3 - mx) + expf(q4 - mx);
  float lse = mx + logf(sum);
  if (lane < CDIM){
    float v = q0;
    if (lane == 1) v = q1;
    if (lane == 2) v = q2;
    if (lane == 3) v = q3;
    if (lane == 4) v = q4;
    out[(size_t)i * CDIM + lane] = v - lse;
  }
}

extern "C" void kernel_launch(void* const* d_in, const int* in_sizes, int n_in,
                              void* d_out, int out_size, void* d_ws, size_t ws_size,
                              hipStream_t stream){
  const float* x  = (const float*)d_in[0];
  const int*   ei = (const int*)d_in[1];
  const float* W1 = (const float*)d_in[2];
  const float* b1 = (const float*)d_in[3];
  const float* W2 = (const float*)d_in[4];
  const float* b2 = (const float*)d_in[5];
  const float* W3 = (const float*)d_in[6];
  const float* b3 = (const float*)d_in[7];
  const float* W4 = (const float*)d_in[8];
  const float* b4 = (const float*)d_in[9];
  float* out = (float*)d_out;

  int N = in_sizes[0] / F_IN;
  int E = in_sizes[1] / 2;
  int NPB = (N + NB - 1) / NB;      // nodes per bucket (98 for N=100000)

  char* ws = (char*)d_ws;
  size_t off = 0;
  auto alloc = [&](size_t bytes) -> char* {
    char* p = ws + off;
    off += (bytes + 255) & ~(size_t)255;
    return p;
  };
  int* bhist = (int*)alloc(((size_t)NB + 1) * 4);  // flag at bhist[NB]
  int* flag  = bhist + NB;
  int* bbase = (int*)alloc(((size_t)NB + 1) * 4);
  int* gwp   = (int*)alloc((size_t)NB * 4);
  int* rowptr= (int*)alloc(((size_t)N + 1) * 4);
  float* dinv= (float*)alloc((size_t)N * 4);
  int* pairs = (int*)alloc((size_t)E * 4);
  int* ssrc  = (int*)alloc((size_t)E * 4);
  unsigned short* hs1 = (unsigned short*)alloc((size_t)N * HDIM * 2);
  unsigned short* hs2 = (unsigned short*)alloc((size_t)N * 8 * 2);
  (void)ws_size; (void)n_in; (void)out_size;

  hipMemsetAsync(bhist, 0, ((size_t)NB + 1) * 4, stream);
  k_detect<<<8, 256, 0, stream>>>(ei, flag, E);
  k_binhist<<<2048, 256, 0, stream>>>(ei, flag, bhist, E, NPB);
  k_scanNB<<<1, 1024, 0, stream>>>(bhist, bbase, gwp, NB);
  k_binscatter<<<SCAT_BLOCKS, SCAT_THREADS, 0, stream>>>(ei, flag, gwp, pairs, E, NPB);
  k_bucket<<<NB, 256, 0, stream>>>(pairs, bbase, rowptr, dinv, ssrc, NPB, N, E);
  k_gemm1<<<(N + 255) / 256, 256, 0, stream>>>(x, W1, dinv, hs1, N);
  k_agg1<<<(N + 3) / 4, 256, 0, stream>>>(hs1, rowptr, ssrc, dinv, b1, W2, hs2, N);
  k_agg2<<<(N + 3) / 4, 256, 0, stream>>>(hs2, rowptr, ssrc, dinv, b2, W3, b3, W4, b4, out, N);
}

// Round 5
// 365.134 us; speedup vs baseline: 3.4268x; 1.0829x over previous
//
#include <hip/hip_runtime.h>
#include <hip/hip_bf16.h>

// GCN: conv1(512->16) + relu + conv2(16->5) + mlp(5->32->5) + log_softmax
// out[dst] = dinv[dst]*(sum_{src in N(dst)} hs[src] + hs[dst]) + b,  hs = dinv*(h@W)
// CSR build via 2-level binning; gemm1 via MFMA with W1 register-resident B-frags.

#define F_IN 512
#define HDIM 16
#define CDIM 5
#define NB   1024      // dst-range buckets
#define SCAT_BLOCKS 512
#define SCAT_THREADS 1024
#define CAP  8192      // per-bucket LDS staging (ints)

typedef __attribute__((ext_vector_type(8))) short short8;
typedef __attribute__((ext_vector_type(4))) float floatx4;

__device__ inline float bf2f(unsigned short u){
  unsigned int i = ((unsigned int)u) << 16; float f; __builtin_memcpy(&f, &i, 4); return f;
}
__device__ inline unsigned short f2bf(float x){
  unsigned int i; __builtin_memcpy(&i, &x, 4);
  unsigned int r = i + 0x7FFFu + ((i >> 16) & 1u);
  return (unsigned short)(r >> 16);
}
__device__ inline float ulo(unsigned int u){
  unsigned int v = u << 16; float f; __builtin_memcpy(&f, &v, 4); return f;
}
__device__ inline float uhi(unsigned int u){
  unsigned int v = u & 0xFFFF0000u; float f; __builtin_memcpy(&f, &v, 4); return f;
}
__device__ inline short8 pack8(float4 u0, float4 u1){
  unsigned short o[8] = {f2bf(u0.x), f2bf(u0.y), f2bf(u0.z), f2bf(u0.w),
                         f2bf(u1.x), f2bf(u1.y), f2bf(u1.z), f2bf(u1.w)};
  short8 r; __builtin_memcpy(&r, o, 16); return r;
}

// ---- detect int64 vs int32 edge_index layout: odd 32-bit words all zero => int64
__global__ void k_detect(const int* __restrict__ ei, int* __restrict__ flag, int E){
  int k = blockIdx.x * blockDim.x + threadIdx.x;
  long long step = E / 2048; if (step < 1) step = 1;
  long long pos = 2LL * ((long long)k * step) + 1;
  if (pos < 2LL * E){
    if (ei[pos] != 0) atomicOr(flag, 1);                   // nonzero odd word => int32
  }
}

// ---- per-bucket histogram (LDS-staged)
__global__ __launch_bounds__(256) void k_binhist(const int* __restrict__ ei, const int* __restrict__ flag,
                                                 int* __restrict__ bhist, int E, int NPB){
  __shared__ int h[NB];
  for (int k = threadIdx.x; k < NB; k += 256) h[k] = 0;
  __syncthreads();
  int is32 = *flag;
  int stride = is32 ? 1 : 2;
  size_t doff = is32 ? (size_t)E : (size_t)2 * E;
  for (long long e = blockIdx.x * blockDim.x + threadIdx.x; e < E;
       e += (long long)gridDim.x * blockDim.x){
    int dst = ei[doff + (size_t)e * stride];
    atomicAdd(&h[dst / NPB], 1);
  }
  __syncthreads();
  for (int k = threadIdx.x; k < NB; k += 256){
    int v = h[k];
    if (v) atomicAdd(&bhist[k], v);
  }
}

// ---- exclusive scan over NB buckets -> bbase, gwp
__global__ __launch_bounds__(1024) void k_scanNB(const int* __restrict__ cnt, int* __restrict__ bbase,
                                                 int* __restrict__ gwp, int nb){
  __shared__ int wsum[16];
  __shared__ int carry_s;
  int t = threadIdx.x, lane = t & 63, w = t >> 6;
  if (t == 0) carry_s = 0;
  __syncthreads();
  for (int base = 0; base < nb; base += 1024){
    int i = base + t;
    int v = (i < nb) ? cnt[i] : 0;
    int xs = v;
    #pragma unroll
    for (int off = 1; off < 64; off <<= 1){
      int y = __shfl_up(xs, off);
      if (lane >= off) xs += y;
    }
    if (lane == 63) wsum[w] = xs;
    __syncthreads();
    int woff = 0;
    for (int k = 0; k < w; ++k) woff += wsum[k];
    int carry = carry_s;
    if (i < nb){
      int excl = carry + woff + xs - v;
      bbase[i] = excl; gwp[i] = excl;
    }
    __syncthreads();
    if (t == 1023) carry_s = carry + woff + xs;
    __syncthreads();
  }
  if (t == 0) bbase[nb] = carry_s;
}

// ---- chunked scatter: each block reserves per-bucket runs, writes packed src|dl<<20
__global__ __launch_bounds__(SCAT_THREADS) void k_binscatter(const int* __restrict__ ei, const int* __restrict__ flag,
                                                    int* __restrict__ gwp, int* __restrict__ pairs,
                                                    int E, int NPB){
  __shared__ int bh[NB];
  __shared__ int bb2[NB];
  int t = threadIdx.x;
  int chunk = (E + gridDim.x - 1) / gridDim.x;
  int e0 = blockIdx.x * chunk;
  int e1 = min(E, e0 + chunk);
  int is32 = *flag;
  int stride = is32 ? 1 : 2;
  size_t doff = is32 ? (size_t)E : (size_t)2 * E;
  for (int k = t; k < NB; k += SCAT_THREADS) bh[k] = 0;
  __syncthreads();
  for (int e = e0 + t; e < e1; e += SCAT_THREADS){
    int dst = ei[doff + (size_t)e * stride];
    atomicAdd(&bh[dst / NPB], 1);
  }
  __syncthreads();
  for (int k = t; k < NB; k += SCAT_THREADS){
    int c = bh[k];
    bb2[k] = c ? atomicAdd(&gwp[k], c) : 0;
    bh[k] = 0;
  }
  __syncthreads();
  for (int e = e0 + t; e < e1; e += SCAT_THREADS){
    int src = ei[(size_t)e * stride];
    int dst = ei[doff + (size_t)e * stride];
    int b = dst / NPB;
    int dl = dst - b * NPB;
    int idx = atomicAdd(&bh[b], 1);
    pairs[bb2[b] + idx] = src | (dl << 20);
  }
}

// ---- per-bucket CSR finalize
__global__ __launch_bounds__(256) void k_bucket(const int* __restrict__ pairs, const int* __restrict__ bbase,
                                                int* __restrict__ rowptr, float* __restrict__ dinv,
                                                int* __restrict__ ssrc, int NPB, int n, int Etot){
  __shared__ int lcnt[128];
  __shared__ int lexcl[129];
  __shared__ int stage[CAP];
  int b = blockIdx.x;
  int t = threadIdx.x;
  int node0 = b * NPB;
  int ebase = bbase[b], eend = bbase[b + 1];
  int cntE = eend - ebase;
  if (t <= NPB) lcnt[t] = 0;
  __syncthreads();
  for (int k = t; k < cntE; k += 256){
    unsigned int v = (unsigned int)pairs[ebase + k];
    atomicAdd(&lcnt[v >> 20], 1);
  }
  __syncthreads();
  if (t == 0){
    int s = 0;
    for (int k = 0; k < NPB; ++k){ lexcl[k] = s; s += lcnt[k]; }
    lexcl[NPB] = s;
  }
  __syncthreads();
  if (t < NPB){
    int node = node0 + t;
    if (node < n){
      rowptr[node] = ebase + lexcl[t];
      dinv[node] = rsqrtf((float)(lcnt[t] + 1));           // +1 self loop
    }
    lcnt[t] = lexcl[t];                                    // reuse as write ptr
  }
  if (b == 0 && t == 0) rowptr[n] = Etot;
  __syncthreads();
  for (int k = t; k < cntE; k += 256){
    unsigned int v = (unsigned int)pairs[ebase + k];
    int idx = atomicAdd(&lcnt[v >> 20], 1);
    int src = (int)(v & 0xFFFFFu);
    if (idx < CAP) stage[idx] = src;
    else ssrc[ebase + idx] = src;
  }
  __syncthreads();
  int m = cntE < CAP ? cntE : CAP;
  for (int k = t; k < m; k += 256) ssrc[ebase + k] = stage[k];
}

// ---- hs1 = dinv * (x @ W1) via MFMA 16x16x32 bf16.
// One wave per 16-row tile. W1 (512x16) lives in registers as 16 B-frags,
// loaded once per wave; x A-frags loaded directly from global (16x128B
// fully-used segments per load step). D: col=lane&15, row=(lane>>4)*4+reg.
__global__ __launch_bounds__(256) void k_gemm1(const float* __restrict__ x, const float* __restrict__ W1,
                                               const float* __restrict__ dinv, unsigned short* __restrict__ hs1,
                                               int n){
  int lane = threadIdx.x & 63;
  int wid = blockIdx.x * 4 + (threadIdx.x >> 6);
  int col = lane & 15;            // A-row / B-col / D-col
  int kg  = lane >> 4;            // k-group (0..3)
  int nt = (n + 15) >> 4;
  // --- load W1 B-frags: frag t covers k = t*32 + kg*8 + e, col = lane&15
  short8 B[16];
  #pragma unroll
  for (int t = 0; t < 16; ++t){
    unsigned short o[8];
    #pragma unroll
    for (int e = 0; e < 8; ++e)
      o[e] = f2bf(W1[(t * 32 + kg * 8 + e) * HDIM + col]);
    __builtin_memcpy(&B[t], o, 16);
  }
  if (wid >= nt) return;
  int row = wid * 16 + col;       // this lane's A row
  const float* xr = x + (size_t)min(row, n - 1) * F_IN;
  floatx4 acc = {0.f, 0.f, 0.f, 0.f};
  #pragma unroll
  for (int t = 0; t < 16; ++t){
    const float4* p = (const float4*)(xr + t * 32 + kg * 8);
    float4 u0 = p[0];
    float4 u1 = p[1];
    acc = __builtin_amdgcn_mfma_f32_16x16x32_bf16(pack8(u0, u1), B[t], acc, 0, 0, 0);
  }
  #pragma unroll
  for (int r = 0; r < 4; ++r){
    int orow = wid * 16 + kg * 4 + r;
    if (orow < n) hs1[(size_t)orow * HDIM + col] = f2bf(dinv[orow] * acc[r]);
  }
}

// ---- conv1 aggregate + b1 + relu + @W2 + dinv scale -> hs2 bf16 [N][8]
// wave per node; 2 lanes per edge (each lane: uint4 = 8 bf16 = half hs1 row).
__global__ __launch_bounds__(256) void k_agg1(const unsigned short* __restrict__ hs1,
    const int* __restrict__ rowptr, const int* __restrict__ ssrc,
    const float* __restrict__ dinv, const float* __restrict__ b1,
    const float* __restrict__ W2, unsigned short* __restrict__ hs2, int n){
  int lane = threadIdx.x & 63;
  int i = blockIdx.x * 4 + (threadIdx.x >> 6);
  if (i >= n) return;
  int slot = lane >> 1, half = lane & 1;
  int beg = rowptr[i], end = rowptr[i + 1];
  const uint4* hv = (const uint4*)hs1;                 // row = 2 uint4
  float acc[8];
  #pragma unroll
  for (int k = 0; k < 8; ++k) acc[k] = 0.f;
  for (int e = beg + slot; e < end; e += 32){
    int src = ssrc[e];
    uint4 v = hv[(size_t)src * 2 + half];
    acc[0] += ulo(v.x); acc[1] += uhi(v.x);
    acc[2] += ulo(v.y); acc[3] += uhi(v.y);
    acc[4] += ulo(v.z); acc[5] += uhi(v.z);
    acc[6] += ulo(v.w); acc[7] += uhi(v.w);
  }
  #pragma unroll
  for (int off = 2; off < 64; off <<= 1){
    #pragma unroll
    for (int k = 0; k < 8; ++k) acc[k] += __shfl_xor(acc[k], off);
  }
  uint4 sv = hv[(size_t)i * 2 + half];
  float self[8] = {ulo(sv.x), uhi(sv.x), ulo(sv.y), uhi(sv.y),
                   ulo(sv.z), uhi(sv.z), ulo(sv.w), uhi(sv.w)};
  float dv = dinv[i];
  const float4* b1v = (const float4*)b1;
  float4 bl = b1v[half * 2], bh = b1v[half * 2 + 1];
  float r[8];
  r[0] = fmaxf(fmaf(dv, acc[0] + self[0], bl.x), 0.f);
  r[1] = fmaxf(fmaf(dv, acc[1] + self[1], bl.y), 0.f);
  r[2] = fmaxf(fmaf(dv, acc[2] + self[2], bl.z), 0.f);
  r[3] = fmaxf(fmaf(dv, acc[3] + self[3], bl.w), 0.f);
  r[4] = fmaxf(fmaf(dv, acc[4] + self[4], bh.x), 0.f);
  r[5] = fmaxf(fmaf(dv, acc[5] + self[5], bh.y), 0.f);
  r[6] = fmaxf(fmaf(dv, acc[6] + self[6], bh.z), 0.f);
  r[7] = fmaxf(fmaf(dv, acc[7] + self[7], bh.w), 0.f);
  const float* w2 = W2 + half * 8 * CDIM;
  float p[CDIM];
  #pragma unroll
  for (int c = 0; c < CDIM; ++c){
    float s = 0.f;
    #pragma unroll
    for (int k = 0; k < 8; ++k) s = fmaf(r[k], w2[k * CDIM + c], s);
    p[c] = s;
  }
  #pragma unroll
  for (int c = 0; c < CDIM; ++c) p[c] += __shfl_xor(p[c], 1);
  if (lane == 0){
    unsigned short o[8];
    #pragma unroll
    for (int c = 0; c < CDIM; ++c) o[c] = f2bf(dv * p[c]);
    o[5] = 0; o[6] = 0; o[7] = 0;
    uint4 v; __builtin_memcpy(&v, o, 16);
    *(uint4*)(hs2 + (size_t)i * 8) = v;
  }
}

// ---- conv2 aggregate + b2 + mlp + log_softmax -> out [N][5] f32
// wave per node; 1 lane per edge (uint4 = full hs2 row).
__global__ __launch_bounds__(256) void k_agg2(const unsigned short* __restrict__ hs2,
    const int* __restrict__ rowptr, const int* __restrict__ ssrc,
    const float* __restrict__ dinv, const float* __restrict__ b2,
    const float* __restrict__ W3, const float* __restrict__ b3,
    const float* __restrict__ W4, const float* __restrict__ b4,
    float* __restrict__ out, int n){
  int lane = threadIdx.x & 63;
  int i = blockIdx.x * 4 + (threadIdx.x >> 6);
  if (i >= n) return;
  int beg = rowptr[i], end = rowptr[i + 1];
  const uint4* hv = (const uint4*)hs2;                 // row = 1 uint4
  float acc[CDIM];
  #pragma unroll
  for (int k = 0; k < CDIM; ++k) acc[k] = 0.f;
  for (int e = beg + lane; e < end; e += 64){
    int src = ssrc[e];
    uint4 v = hv[src];
    acc[0] += ulo(v.x); acc[1] += uhi(v.x);
    acc[2] += ulo(v.y); acc[3] += uhi(v.y);
    acc[4] += ulo(v.z);
  }
  #pragma unroll
  for (int off = 1; off < 64; off <<= 1){
    #pragma unroll
    for (int k = 0; k < CDIM; ++k) acc[k] += __shfl_xor(acc[k], off);
  }
  float dv = dinv[i];
  uint4 sv = hv[i];
  float a0 = fmaf(dv, acc[0] + ulo(sv.x), b2[0]);
  float a1 = fmaf(dv, acc[1] + uhi(sv.x), b2[1]);
  float a2 = fmaf(dv, acc[2] + ulo(sv.y), b2[2]);
  float a3 = fmaf(dv, acc[3] + uhi(sv.y), b2[3]);
  float a4 = fmaf(dv, acc[4] + ulo(sv.z), b2[4]);
  int m = lane & 31;
  float h3 = b3[m];
  h3 = fmaf(a0, W3[0 * 32 + m], h3);
  h3 = fmaf(a1, W3[1 * 32 + m], h3);
  h3 = fmaf(a2, W3[2 * 32 + m], h3);
  h3 = fmaf(a3, W3[3 * 32 + m], h3);
  h3 = fmaf(a4, W3[4 * 32 + m], h3);
  h3 = fmaxf(h3, 0.f);
  float q0 = h3 * W4[m * CDIM + 0], q1 = h3 * W4[m * CDIM + 1], q2 = h3 * W4[m * CDIM + 2];
  float q3 = h3 * W4[m * CDIM + 3], q4 = h3 * W4[m * CDIM + 4];
  #pragma unroll
  for (int off = 1; off < 32; off <<= 1){
    q0 += __shfl_xor(q0, off); q1 += __shfl_xor(q1, off); q2 += __shfl_xor(q2, off);
    q3 += __shfl_xor(q3, off); q4 += __shfl_xor(q4, off);
  }
  q0 += b4[0]; q1 += b4[1]; q2 += b4[2]; q3 += b4[3]; q4 += b4[4];
  float mx = fmaxf(fmaxf(fmaxf(q0, q1), fmaxf(q2, q3)), q4);
  float sum = expf(q0 - mx) + expf(q1 - mx) + expf(q2 - mx) + expf(q3 - mx) + expf(q4 - mx);
  float lse = mx + logf(sum);
  if (lane < CDIM){
    float v = q0;
    if (lane == 1) v = q1;
    if (lane == 2) v = q2;
    if (lane == 3) v = q3;
    if (lane == 4) v = q4;
    out[(size_t)i * CDIM + lane] = v - lse;
  }
}

extern "C" void kernel_launch(void* const* d_in, const int* in_sizes, int n_in,
                              void* d_out, int out_size, void* d_ws, size_t ws_size,
                              hipStream_t stream){
  const float* x  = (const float*)d_in[0];
  const int*   ei = (const int*)d_in[1];
  const float* W1 = (const float*)d_in[2];
  const float* b1 = (const float*)d_in[3];
  const float* W2 = (const float*)d_in[4];
  const float* b2 = (const float*)d_in[5];
  const float* W3 = (const float*)d_in[6];
  const float* b3 = (const float*)d_in[7];
  const float* W4 = (const float*)d_in[8];
  const float* b4 = (const float*)d_in[9];
  float* out = (float*)d_out;

  int N = in_sizes[0] / F_IN;
  int E = in_sizes[1] / 2;
  int NPB = (N + NB - 1) / NB;      // nodes per bucket (98 for N=100000)

  char* ws = (char*)d_ws;
  size_t off = 0;
  auto alloc = [&](size_t bytes) -> char* {
    char* p = ws + off;
    off += (bytes + 255) & ~(size_t)255;
    return p;
  };
  int* bhist = (int*)alloc(((size_t)NB + 1) * 4);  // flag at bhist[NB]
  int* flag  = bhist + NB;
  int* bbase = (int*)alloc(((size_t)NB + 1) * 4);
  int* gwp   = (int*)alloc((size_t)NB * 4);
  int* rowptr= (int*)alloc(((size_t)N + 1) * 4);
  float* dinv= (float*)alloc((size_t)N * 4);
  int* pairs = (int*)alloc((size_t)E * 4);
  int* ssrc  = (int*)alloc((size_t)E * 4);
  unsigned short* hs1 = (unsigned short*)alloc((size_t)N * HDIM * 2);
  unsigned short* hs2 = (unsigned short*)alloc((size_t)N * 8 * 2);
  (void)ws_size; (void)n_in; (void)out_size;

  hipMemsetAsync(bhist, 0, ((size_t)NB + 1) * 4, stream);
  k_detect<<<8, 256, 0, stream>>>(ei, flag, E);
  k_binhist<<<2048, 256, 0, stream>>>(ei, flag, bhist, E, NPB);
  k_scanNB<<<1, 1024, 0, stream>>>(bhist, bbase, gwp, NB);
  k_binscatter<<<SCAT_BLOCKS, SCAT_THREADS, 0, stream>>>(ei, flag, gwp, pairs, E, NPB);
  k_bucket<<<NB, 256, 0, stream>>>(pairs, bbase, rowptr, dinv, ssrc, NPB, N, E);
  int nt = (N + 15) / 16;
  k_gemm1<<<(nt + 3) / 4, 256, 0, stream>>>(x, W1, dinv, hs1, N);
  k_agg1<<<(N + 3) / 4, 256, 0, stream>>>(hs1, rowptr, ssrc, dinv, b1, W2, hs2, N);
  k_agg2<<<(N + 3) / 4, 256, 0, stream>>>(hs2, rowptr, ssrc, dinv, b2, W3, b3, W4, b4, out, N);
}

// Round 6
// 340.372 us; speedup vs baseline: 3.6761x; 1.0727x over previous
//
#include <hip/hip_runtime.h>
#include <hip/hip_bf16.h>

// GCN: conv1(512->16) + relu + conv2(16->5) + mlp(5->32->5) + log_softmax
// out[dst] = dinv[dst]*(sum_{src in N(dst)} hs[src] + hs[dst]) + b,  hs = dinv*(h@W)
// CSR build via 2-level binning; binscatter = block-local counting sort with
// coalesced run copy-out; gemm1 via MFMA with W1 register-resident B-frags.

#define F_IN 512
#define HDIM 16
#define CDIM 5
#define NB   1024      // dst-range buckets
#define GWP_STRIDE 16  // pad gwp counters to one per 64B line
#define SCHUNK 12288   // edges per binscatter block (48KB LDS stage)
#define CAP  8192      // per-bucket LDS staging in k_bucket (ints)

typedef __attribute__((ext_vector_type(8))) short short8;
typedef __attribute__((ext_vector_type(4))) float floatx4;

__device__ inline float bf2f(unsigned short u){
  unsigned int i = ((unsigned int)u) << 16; float f; __builtin_memcpy(&f, &i, 4); return f;
}
__device__ inline unsigned short f2bf(float x){
  unsigned int i; __builtin_memcpy(&i, &x, 4);
  unsigned int r = i + 0x7FFFu + ((i >> 16) & 1u);
  return (unsigned short)(r >> 16);
}
__device__ inline float ulo(unsigned int u){
  unsigned int v = u << 16; float f; __builtin_memcpy(&f, &v, 4); return f;
}
__device__ inline float uhi(unsigned int u){
  unsigned int v = u & 0xFFFF0000u; float f; __builtin_memcpy(&f, &v, 4); return f;
}
__device__ inline short8 pack8(float4 u0, float4 u1){
  unsigned short o[8] = {f2bf(u0.x), f2bf(u0.y), f2bf(u0.z), f2bf(u0.w),
                         f2bf(u1.x), f2bf(u1.y), f2bf(u1.z), f2bf(u1.w)};
  short8 r; __builtin_memcpy(&r, o, 16); return r;
}

// ---- detect int64 vs int32 edge_index layout: odd 32-bit words all zero => int64
__global__ void k_detect(const int* __restrict__ ei, int* __restrict__ flag, int E){
  int k = blockIdx.x * blockDim.x + threadIdx.x;
  long long step = E / 2048; if (step < 1) step = 1;
  long long pos = 2LL * ((long long)k * step) + 1;
  if (pos < 2LL * E){
    if (ei[pos] != 0) atomicOr(flag, 1);                   // nonzero odd word => int32
  }
}

// ---- per-bucket histogram (LDS-staged)
__global__ __launch_bounds__(256) void k_binhist(const int* __restrict__ ei, const int* __restrict__ flag,
                                                 int* __restrict__ bhist, int E, int NPB){
  __shared__ int h[NB];
  for (int k = threadIdx.x; k < NB; k += 256) h[k] = 0;
  __syncthreads();
  int is32 = *flag;
  int stride = is32 ? 1 : 2;
  size_t doff = is32 ? (size_t)E : (size_t)2 * E;
  for (long long e = blockIdx.x * blockDim.x + threadIdx.x; e < E;
       e += (long long)gridDim.x * blockDim.x){
    int dst = ei[doff + (size_t)e * stride];
    atomicAdd(&h[dst / NPB], 1);
  }
  __syncthreads();
  for (int k = threadIdx.x; k < NB; k += 256){
    int v = h[k];
    if (v) atomicAdd(&bhist[k], v);
  }
}

// ---- exclusive scan over NB buckets -> bbase, gwp (gwp padded: 1 counter / 64B)
__global__ __launch_bounds__(1024) void k_scanNB(const int* __restrict__ cnt, int* __restrict__ bbase,
                                                 int* __restrict__ gwp, int nb){
  __shared__ int wsum[16];
  int t = threadIdx.x, lane = t & 63, w = t >> 6;
  int v = (t < nb) ? cnt[t] : 0;
  int xs = v;
  #pragma unroll
  for (int off = 1; off < 64; off <<= 1){
    int y = __shfl_up(xs, off);
    if (lane >= off) xs += y;
  }
  if (lane == 63) wsum[w] = xs;
  __syncthreads();
  int woff = 0;
  for (int k = 0; k < w; ++k) woff += wsum[k];
  if (t < nb){
    int excl = woff + xs - v;
    bbase[t] = excl;
    gwp[t * GWP_STRIDE] = excl;
  }
  if (t == 1023) bbase[nb] = woff + xs;
}

// ---- block-local counting sort: hist -> scan -> LDS scatter -> coalesced copy-out
__global__ __launch_bounds__(1024) void k_binscatter(const int* __restrict__ ei, const int* __restrict__ flag,
                                                     int* __restrict__ gwp, int* __restrict__ pairs,
                                                     int E, int NPB){
  __shared__ int bh[NB];          // hist, then write-ptr
  __shared__ int lex[NB + 1];     // local exclusive scan
  __shared__ int bb2[NB];         // global base per bucket
  __shared__ int wsum[16];
  __shared__ int stage[SCHUNK];
  int t = threadIdx.x;
  int e0 = blockIdx.x * SCHUNK;
  int e1 = min(E, e0 + SCHUNK);
  int cnt = e1 - e0;
  if (cnt <= 0) return;
  int is32 = *flag;
  int stride = is32 ? 1 : 2;
  size_t doff = is32 ? (size_t)E : (size_t)2 * E;
  bh[t] = 0;
  __syncthreads();
  // A: local hist
  for (int e = e0 + t; e < e1; e += 1024){
    int dst = ei[doff + (size_t)e * stride];
    atomicAdd(&bh[dst / NPB], 1);
  }
  __syncthreads();
  // B: block scan (t == bucket), reserve global runs
  {
    int lane = t & 63, w = t >> 6;
    int v = bh[t];
    int xs = v;
    #pragma unroll
    for (int off = 1; off < 64; off <<= 1){
      int y = __shfl_up(xs, off);
      if (lane >= off) xs += y;
    }
    if (lane == 63) wsum[w] = xs;
    __syncthreads();
    int woff = 0;
    for (int k = 0; k < w; ++k) woff += wsum[k];
    int excl = woff + xs - v;
    lex[t] = excl;
    if (t == 1023) lex[NB] = woff + xs;
    bb2[t] = v ? atomicAdd(&gwp[t * GWP_STRIDE], v) : 0;
    __syncthreads();              // all reads of bh done before overwrite
    bh[t] = excl;                 // becomes local write ptr
  }
  __syncthreads();
  // C: scatter into LDS stage (packed src | dl<<20)
  for (int e = e0 + t; e < e1; e += 1024){
    int src = ei[(size_t)e * stride];
    int dst = ei[doff + (size_t)e * stride];
    int b = dst / NPB;
    int dl = dst - b * NPB;
    int idx = atomicAdd(&bh[b], 1);
    stage[idx] = src | (dl << 20);
  }
  __syncthreads();
  // D: copy-out; consecutive k -> consecutive addresses within each run
  for (int k = t; k < cnt; k += 1024){
    int lo = 0, hi = NB;          // find bucket: largest b with lex[b] <= k
    while (hi - lo > 1){
      int mid = (lo + hi) >> 1;
      if (lex[mid] <= k) lo = mid; else hi = mid;
    }
    pairs[bb2[lo] + (k - lex[lo])] = stage[k];
  }
}

// ---- per-bucket CSR finalize
__global__ __launch_bounds__(256) void k_bucket(const int* __restrict__ pairs, const int* __restrict__ bbase,
                                                int* __restrict__ rowptr, float* __restrict__ dinv,
                                                int* __restrict__ ssrc, int NPB, int n, int Etot){
  __shared__ int lcnt[128];
  __shared__ int lexcl[129];
  __shared__ int stage[CAP];
  int b = blockIdx.x;
  int t = threadIdx.x;
  int node0 = b * NPB;
  int ebase = bbase[b], eend = bbase[b + 1];
  int cntE = eend - ebase;
  if (t <= NPB) lcnt[t] = 0;
  __syncthreads();
  for (int k = t; k < cntE; k += 256){
    unsigned int v = (unsigned int)pairs[ebase + k];
    atomicAdd(&lcnt[v >> 20], 1);
  }
  __syncthreads();
  if (t == 0){
    int s = 0;
    for (int k = 0; k < NPB; ++k){ lexcl[k] = s; s += lcnt[k]; }
    lexcl[NPB] = s;
  }
  __syncthreads();
  if (t < NPB){
    int node = node0 + t;
    if (node < n){
      rowptr[node] = ebase + lexcl[t];
      dinv[node] = rsqrtf((float)(lcnt[t] + 1));           // +1 self loop
    }
    lcnt[t] = lexcl[t];                                    // reuse as write ptr
  }
  if (b == 0 && t == 0) rowptr[n] = Etot;
  __syncthreads();
  for (int k = t; k < cntE; k += 256){
    unsigned int v = (unsigned int)pairs[ebase + k];
    int idx = atomicAdd(&lcnt[v >> 20], 1);
    int src = (int)(v & 0xFFFFFu);
    if (idx < CAP) stage[idx] = src;
    else ssrc[ebase + idx] = src;
  }
  __syncthreads();
  int m = cntE < CAP ? cntE : CAP;
  for (int k = t; k < m; k += 256) ssrc[ebase + k] = stage[k];
}

// ---- hs1 = dinv * (x @ W1) via MFMA 16x16x32 bf16.
__global__ __launch_bounds__(256) void k_gemm1(const float* __restrict__ x, const float* __restrict__ W1,
                                               const float* __restrict__ dinv, unsigned short* __restrict__ hs1,
                                               int n){
  int lane = threadIdx.x & 63;
  int wid = blockIdx.x * 4 + (threadIdx.x >> 6);
  int col = lane & 15;            // A-row / B-col / D-col
  int kg  = lane >> 4;            // k-group (0..3)
  int nt = (n + 15) >> 4;
  short8 B[16];
  #pragma unroll
  for (int t = 0; t < 16; ++t){
    unsigned short o[8];
    #pragma unroll
    for (int e = 0; e < 8; ++e)
      o[e] = f2bf(W1[(t * 32 + kg * 8 + e) * HDIM + col]);
    __builtin_memcpy(&B[t], o, 16);
  }
  if (wid >= nt) return;
  int row = wid * 16 + col;
  const float* xr = x + (size_t)min(row, n - 1) * F_IN;
  floatx4 acc = {0.f, 0.f, 0.f, 0.f};
  #pragma unroll
  for (int t = 0; t < 16; ++t){
    const float4* p = (const float4*)(xr + t * 32 + kg * 8);
    float4 u0 = p[0];
    float4 u1 = p[1];
    acc = __builtin_amdgcn_mfma_f32_16x16x32_bf16(pack8(u0, u1), B[t], acc, 0, 0, 0);
  }
  #pragma unroll
  for (int r = 0; r < 4; ++r){
    int orow = wid * 16 + kg * 4 + r;
    if (orow < n) hs1[(size_t)orow * HDIM + col] = f2bf(dinv[orow] * acc[r]);
  }
}

// ---- conv1 aggregate + b1 + relu + @W2 + dinv scale -> hs2 bf16 [N][8]
__global__ __launch_bounds__(256) void k_agg1(const unsigned short* __restrict__ hs1,
    const int* __restrict__ rowptr, const int* __restrict__ ssrc,
    const float* __restrict__ dinv, const float* __restrict__ b1,
    const float* __restrict__ W2, unsigned short* __restrict__ hs2, int n){
  int lane = threadIdx.x & 63;
  int i = blockIdx.x * 4 + (threadIdx.x >> 6);
  if (i >= n) return;
  int slot = lane >> 1, half = lane & 1;
  int beg = rowptr[i], end = rowptr[i + 1];
  const uint4* hv = (const uint4*)hs1;                 // row = 2 uint4
  float acc[8];
  #pragma unroll
  for (int k = 0; k < 8; ++k) acc[k] = 0.f;
  for (int e = beg + slot; e < end; e += 32){
    int src = ssrc[e];
    uint4 v = hv[(size_t)src * 2 + half];
    acc[0] += ulo(v.x); acc[1] += uhi(v.x);
    acc[2] += ulo(v.y); acc[3] += uhi(v.y);
    acc[4] += ulo(v.z); acc[5] += uhi(v.z);
    acc[6] += ulo(v.w); acc[7] += uhi(v.w);
  }
  #pragma unroll
  for (int off = 2; off < 64; off <<= 1){
    #pragma unroll
    for (int k = 0; k < 8; ++k) acc[k] += __shfl_xor(acc[k], off);
  }
  uint4 sv = hv[(size_t)i * 2 + half];
  float self[8] = {ulo(sv.x), uhi(sv.x), ulo(sv.y), uhi(sv.y),
                   ulo(sv.z), uhi(sv.z), ulo(sv.w), uhi(sv.w)};
  float dv = dinv[i];
  const float4* b1v = (const float4*)b1;
  float4 bl = b1v[half * 2], bh = b1v[half * 2 + 1];
  float r[8];
  r[0] = fmaxf(fmaf(dv, acc[0] + self[0], bl.x), 0.f);
  r[1] = fmaxf(fmaf(dv, acc[1] + self[1], bl.y), 0.f);
  r[2] = fmaxf(fmaf(dv, acc[2] + self[2], bl.z), 0.f);
  r[3] = fmaxf(fmaf(dv, acc[3] + self[3], bl.w), 0.f);
  r[4] = fmaxf(fmaf(dv, acc[4] + self[4], bh.x), 0.f);
  r[5] = fmaxf(fmaf(dv, acc[5] + self[5], bh.y), 0.f);
  r[6] = fmaxf(fmaf(dv, acc[6] + self[6], bh.z), 0.f);
  r[7] = fmaxf(fmaf(dv, acc[7] + self[7], bh.w), 0.f);
  const float* w2 = W2 + half * 8 * CDIM;
  float p[CDIM];
  #pragma unroll
  for (int c = 0; c < CDIM; ++c){
    float s = 0.f;
    #pragma unroll
    for (int k = 0; k < 8; ++k) s = fmaf(r[k], w2[k * CDIM + c], s);
    p[c] = s;
  }
  #pragma unroll
  for (int c = 0; c < CDIM; ++c) p[c] += __shfl_xor(p[c], 1);
  if (lane == 0){
    unsigned short o[8];
    #pragma unroll
    for (int c = 0; c < CDIM; ++c) o[c] = f2bf(dv * p[c]);
    o[5] = 0; o[6] = 0; o[7] = 0;
    uint4 v; __builtin_memcpy(&v, o, 16);
    *(uint4*)(hs2 + (size_t)i * 8) = v;
  }
}

// ---- conv2 aggregate + b2 + mlp + log_softmax -> out [N][5] f32
__global__ __launch_bounds__(256) void k_agg2(const unsigned short* __restrict__ hs2,
    const int* __restrict__ rowptr, const int* __restrict__ ssrc,
    const float* __restrict__ dinv, const float* __restrict__ b2,
    const float* __restrict__ W3, const float* __restrict__ b3,
    const float* __restrict__ W4, const float* __restrict__ b4,
    float* __restrict__ out, int n){
  int lane = threadIdx.x & 63;
  int i = blockIdx.x * 4 + (threadIdx.x >> 6);
  if (i >= n) return;
  int beg = rowptr[i], end = rowptr[i + 1];
  const uint4* hv = (const uint4*)hs2;                 // row = 1 uint4
  float acc[CDIM];
  #pragma unroll
  for (int k = 0; k < CDIM; ++k) acc[k] = 0.f;
  for (int e = beg + lane; e < end; e += 64){
    int src = ssrc[e];
    uint4 v = hv[src];
    acc[0] += ulo(v.x); acc[1] += uhi(v.x);
    acc[2] += ulo(v.y); acc[3] += uhi(v.y);
    acc[4] += ulo(v.z);
  }
  #pragma unroll
  for (int off = 1; off < 64; off <<= 1){
    #pragma unroll
    for (int k = 0; k < CDIM; ++k) acc[k] += __shfl_xor(acc[k], off);
  }
  float dv = dinv[i];
  uint4 sv = hv[i];
  float a0 = fmaf(dv, acc[0] + ulo(sv.x), b2[0]);
  float a1 = fmaf(dv, acc[1] + uhi(sv.x), b2[1]);
  float a2 = fmaf(dv, acc[2] + ulo(sv.y), b2[2]);
  float a3 = fmaf(dv, acc[3] + uhi(sv.y), b2[3]);
  float a4 = fmaf(dv, acc[4] + ulo(sv.z), b2[4]);
  int m = lane & 31;
  float h3 = b3[m];
  h3 = fmaf(a0, W3[0 * 32 + m], h3);
  h3 = fmaf(a1, W3[1 * 32 + m], h3);
  h3 = fmaf(a2, W3[2 * 32 + m], h3);
  h3 = fmaf(a3, W3[3 * 32 + m], h3);
  h3 = fmaf(a4, W3[4 * 32 + m], h3);
  h3 = fmaxf(h3, 0.f);
  float q0 = h3 * W4[m * CDIM + 0], q1 = h3 * W4[m * CDIM + 1], q2 = h3 * W4[m * CDIM + 2];
  float q3 = h3 * W4[m * CDIM + 3], q4 = h3 * W4[m * CDIM + 4];
  #pragma unroll
  for (int off = 1; off < 32; off <<= 1){
    q0 += __shfl_xor(q0, off); q1 += __shfl_xor(q1, off); q2 += __shfl_xor(q2, off);
    q3 += __shfl_xor(q3, off); q4 += __shfl_xor(q4, off);
  }
  q0 += b4[0]; q1 += b4[1]; q2 += b4[2]; q3 += b4[3]; q4 += b4[4];
  float mx = fmaxf(fmaxf(fmaxf(q0, q1), fmaxf(q2, q3)), q4);
  float sum = expf(q0 - mx) + expf(q1 - mx) + expf(q2 - mx) + expf(q3 - mx) + expf(q4 - mx);
  float lse = mx + logf(sum);
  if (lane < CDIM){
    float v = q0;
    if (lane == 1) v = q1;
    if (lane == 2) v = q2;
    if (lane == 3) v = q3;
    if (lane == 4) v = q4;
    out[(size_t)i * CDIM + lane] = v - lse;
  }
}

extern "C" void kernel_launch(void* const* d_in, const int* in_sizes, int n_in,
                              void* d_out, int out_size, void* d_ws, size_t ws_size,
                              hipStream_t stream){
  const float* x  = (const float*)d_in[0];
  const int*   ei = (const int*)d_in[1];
  const float* W1 = (const float*)d_in[2];
  const float* b1 = (const float*)d_in[3];
  const float* W2 = (const float*)d_in[4];
  const float* b2 = (const float*)d_in[5];
  const float* W3 = (const float*)d_in[6];
  const float* b3 = (const float*)d_in[7];
  const float* W4 = (const float*)d_in[8];
  const float* b4 = (const float*)d_in[9];
  float* out = (float*)d_out;

  int N = in_sizes[0] / F_IN;
  int E = in_sizes[1] / 2;
  int NPB = (N + NB - 1) / NB;      // nodes per bucket (98 for N=100000)

  char* ws = (char*)d_ws;
  size_t off = 0;
  auto alloc = [&](size_t bytes) -> char* {
    char* p = ws + off;
    off += (bytes + 255) & ~(size_t)255;
    return p;
  };
  int* bhist = (int*)alloc(((size_t)NB + 1) * 4);  // flag at bhist[NB]
  int* flag  = bhist + NB;
  int* bbase = (int*)alloc(((size_t)NB + 1) * 4);
  int* gwp   = (int*)alloc((size_t)NB * GWP_STRIDE * 4);
  int* rowptr= (int*)alloc(((size_t)N + 1) * 4);
  float* dinv= (float*)alloc((size_t)N * 4);
  int* pairs = (int*)alloc((size_t)E * 4);
  int* ssrc  = (int*)alloc((size_t)E * 4);
  unsigned short* hs1 = (unsigned short*)alloc((size_t)N * HDIM * 2);
  unsigned short* hs2 = (unsigned short*)alloc((size_t)N * 8 * 2);
  (void)ws_size; (void)n_in; (void)out_size;

  hipMemsetAsync(bhist, 0, ((size_t)NB + 1) * 4, stream);
  k_detect<<<8, 256, 0, stream>>>(ei, flag, E);
  k_binhist<<<2048, 256, 0, stream>>>(ei, flag, bhist, E, NPB);
  k_scanNB<<<1, 1024, 0, stream>>>(bhist, bbase, gwp, NB);
  int sblocks = (E + SCHUNK - 1) / SCHUNK;
  k_binscatter<<<sblocks, 1024, 0, stream>>>(ei, flag, gwp, pairs, E, NPB);
  k_bucket<<<NB, 256, 0, stream>>>(pairs, bbase, rowptr, dinv, ssrc, NPB, N, E);
  int nt = (N + 15) / 16;
  k_gemm1<<<(nt + 3) / 4, 256, 0, stream>>>(x, W1, dinv, hs1, N);
  k_agg1<<<(N + 3) / 4, 256, 0, stream>>>(hs1, rowptr, ssrc, dinv, b1, W2, hs2, N);
  k_agg2<<<(N + 3) / 4, 256, 0, stream>>>(hs2, rowptr, ssrc, dinv, b2, W3, b3, W4, b4, out, N);
}

// Round 7
// 282.281 us; speedup vs baseline: 4.4326x; 1.2058x over previous
//
#include <hip/hip_runtime.h>
#include <hip/hip_bf16.h>

// GCN: conv1(512->16) + relu + conv2(16->5) + mlp(5->32->5) + log_softmax
// out[dst] = dinv[dst]*(sum_{src in N(dst)} hs[src] + hs[dst]) + b,  hs = dinv*(h@W)
// CSR build: segmented 2-level bucket sort (no pre-histogram pass):
//   detect -> binscatter(seg, counting-sort per block) -> scanNB -> bucket(compact)
// gemm1 via MFMA with W1 register-resident B-frags, multi-tile per wave.

#define F_IN 512
#define HDIM 16
#define CDIM 5
#define NB   1024      // dst-range buckets
#define SEG  8192      // per-bucket segment capacity in pairs[] (mean load 6250)
#define GWP_STRIDE 16  // pad gwp counters to one per 64B line
#define SCHUNK 12288   // edges per binscatter block (48KB LDS stage)
#define CAP  8192      // per-bucket LDS staging in k_bucket (ints)

typedef __attribute__((ext_vector_type(8))) short short8;
typedef __attribute__((ext_vector_type(4))) float floatx4;

__device__ inline float bf2f(unsigned short u){
  unsigned int i = ((unsigned int)u) << 16; float f; __builtin_memcpy(&f, &i, 4); return f;
}
__device__ inline unsigned short f2bf(float x){
  unsigned int i; __builtin_memcpy(&i, &x, 4);
  unsigned int r = i + 0x7FFFu + ((i >> 16) & 1u);
  return (unsigned short)(r >> 16);
}
__device__ inline float ulo(unsigned int u){
  unsigned int v = u << 16; float f; __builtin_memcpy(&f, &v, 4); return f;
}
__device__ inline float uhi(unsigned int u){
  unsigned int v = u & 0xFFFF0000u; float f; __builtin_memcpy(&f, &v, 4); return f;
}
__device__ inline short8 pack8(float4 u0, float4 u1){
  unsigned short o[8] = {f2bf(u0.x), f2bf(u0.y), f2bf(u0.z), f2bf(u0.w),
                         f2bf(u1.x), f2bf(u1.y), f2bf(u1.z), f2bf(u1.w)};
  short8 r; __builtin_memcpy(&r, o, 16); return r;
}

// ---- detect int64 vs int32 layout (odd words all zero => int64) + init gwp bases
__global__ void k_detect(const int* __restrict__ ei, int* __restrict__ flag,
                         int* __restrict__ gwp, int E){
  int k = blockIdx.x * blockDim.x + threadIdx.x;           // 2048 threads
  if (k < NB) gwp[k * GWP_STRIDE] = k * SEG;
  long long step = E / 2048; if (step < 1) step = 1;
  long long pos = 2LL * ((long long)k * step) + 1;
  if (pos < 2LL * E){
    if (ei[pos] != 0) atomicOr(flag, 1);                   // nonzero odd word => int32
  }
}

// ---- block-local counting sort into segmented pairs[] (no pre-histogram needed)
__global__ __launch_bounds__(1024) void k_binscatter(const int* __restrict__ ei, const int* __restrict__ flag,
                                                     int* __restrict__ gwp, int* __restrict__ pairs,
                                                     int E, int NPB){
  __shared__ int bh[NB];          // hist, then local write-ptr
  __shared__ int lex[NB + 1];     // local exclusive scan
  __shared__ int bb2[NB];         // reserved global base per bucket
  __shared__ int wsum[16];
  __shared__ int stage[SCHUNK];
  int t = threadIdx.x;
  int e0 = blockIdx.x * SCHUNK;
  int e1 = min(E, e0 + SCHUNK);
  int cnt = e1 - e0;
  if (cnt <= 0) return;
  int is32 = *flag;
  const uint2* ei2 = (const uint2*)ei;
  bh[t] = 0;
  __syncthreads();
  // A: local hist over dst
  for (int e = e0 + t; e < e1; e += 1024){
    int dst = is32 ? ei[(size_t)E + e] : (int)ei2[(size_t)E + e].x;
    atomicAdd(&bh[dst / NPB], 1);
  }
  __syncthreads();
  // B: block scan (t == bucket), reserve global runs in the bucket's segment
  {
    int lane = t & 63, w = t >> 6;
    int v = bh[t];
    int xs = v;
    #pragma unroll
    for (int off = 1; off < 64; off <<= 1){
      int y = __shfl_up(xs, off);
      if (lane >= off) xs += y;
    }
    if (lane == 63) wsum[w] = xs;
    __syncthreads();
    int woff = 0;
    for (int k = 0; k < w; ++k) woff += wsum[k];
    int excl = woff + xs - v;
    lex[t] = excl;
    if (t == 1023) lex[NB] = woff + xs;
    bb2[t] = v ? atomicAdd(&gwp[t * GWP_STRIDE], v) : 0;
    __syncthreads();              // all reads of bh done before overwrite
    bh[t] = excl;                 // becomes local write ptr
  }
  __syncthreads();
  // C: scatter into LDS stage (packed src | dl<<20)
  for (int e = e0 + t; e < e1; e += 1024){
    int src, dst;
    if (is32){ src = ei[e]; dst = ei[(size_t)E + e]; }
    else     { src = (int)ei2[e].x; dst = (int)ei2[(size_t)E + e].x; }
    int b = dst / NPB;
    int dl = dst - b * NPB;
    int idx = atomicAdd(&bh[b], 1);
    stage[idx] = src | (dl << 20);
  }
  __syncthreads();
  // D: coalesced copy-out (consecutive k -> consecutive addresses within a run)
  for (int k = t; k < cnt; k += 1024){
    int lo = 0, hi = NB;          // largest b with lex[b] <= k
    while (hi - lo > 1){
      int mid = (lo + hi) >> 1;
      if (lex[mid] <= k) lo = mid; else hi = mid;
    }
    pairs[bb2[lo] + (k - lex[lo])] = stage[k];
  }
}

// ---- compact scan over buckets: count = gwp_final - segment base
__global__ __launch_bounds__(1024) void k_scanNB(const int* __restrict__ gwp, int* __restrict__ bbase,
                                                 int nb){
  __shared__ int wsum[16];
  int t = threadIdx.x, lane = t & 63, w = t >> 6;
  int v = (t < nb) ? (gwp[t * GWP_STRIDE] - t * SEG) : 0;
  int xs = v;
  #pragma unroll
  for (int off = 1; off < 64; off <<= 1){
    int y = __shfl_up(xs, off);
    if (lane >= off) xs += y;
  }
  if (lane == 63) wsum[w] = xs;
  __syncthreads();
  int woff = 0;
  for (int k = 0; k < w; ++k) woff += wsum[k];
  if (t < nb) bbase[t] = woff + xs - v;
  if (t == 1023) bbase[nb] = woff + xs;
}

// ---- per-bucket CSR finalize: 4-way sub-hist, scan, LDS-staged sort, coalesced flush
__global__ __launch_bounds__(512) void k_bucket(const int* __restrict__ pairs, const int* __restrict__ bbase,
                                                int* __restrict__ rowptr, float* __restrict__ dinv,
                                                int* __restrict__ ssrc, int NPB, int n, int Etot){
  __shared__ int lcnt[4][128];    // sub-hists, then sub-write-ptrs
  __shared__ int tot[128];
  __shared__ int lexcl[129];
  __shared__ int stage[CAP];
  int b = blockIdx.x;
  int t = threadIdx.x;
  int g = t >> 7;                 // 4 groups of 128 threads
  int node0 = b * NPB;
  int pbase = b * SEG;
  int obase = bbase[b];
  int cntE = bbase[b + 1] - obase;
  lcnt[g][t & 127] = 0;
  __syncthreads();
  for (int k = t; k < cntE; k += 512){
    unsigned int v = (unsigned int)pairs[pbase + k];
    atomicAdd(&lcnt[g][v >> 20], 1);
  }
  __syncthreads();
  if (t < 128){
    int s0 = lcnt[0][t], s1 = lcnt[1][t], s2 = lcnt[2][t], s3 = lcnt[3][t];
    tot[t] = s0 + s1 + s2 + s3;
    lcnt[0][t] = 0; lcnt[1][t] = s0; lcnt[2][t] = s0 + s1; lcnt[3][t] = s0 + s1 + s2;
  }
  __syncthreads();
  if (t == 0){
    int s = 0;
    for (int k = 0; k < NPB; ++k){ lexcl[k] = s; s += tot[k]; }
    lexcl[NPB] = s;
  }
  __syncthreads();
  if (t < NPB){
    int node = node0 + t;
    if (node < n){
      rowptr[node] = obase + lexcl[t];
      dinv[node] = rsqrtf((float)(tot[t] + 1));            // +1 self loop
    }
  }
  lcnt[g][t & 127] += lexcl[t & 127];                      // sub-write-ptr = lexcl + group offset
  if (b == 0 && t == 0) rowptr[n] = Etot;
  __syncthreads();
  for (int k = t; k < cntE; k += 512){
    unsigned int v = (unsigned int)pairs[pbase + k];
    int idx = atomicAdd(&lcnt[g][v >> 20], 1);
    int src = (int)(v & 0xFFFFFu);
    if (idx < CAP) stage[idx] = src;
    else ssrc[obase + idx] = src;
  }
  __syncthreads();
  int m = cntE < CAP ? cntE : CAP;
  for (int k = t; k < m; k += 512) ssrc[obase + k] = stage[k];
}

// ---- hs1 = dinv * (x @ W1) via MFMA 16x16x32 bf16, multi-tile per wave.
// W1 (512x16) in registers as 16 B-frags (loaded once); x A-frags direct from
// global. D: col=lane&15, row=(lane>>4)*4+reg.
__global__ __launch_bounds__(256) void k_gemm1(const float* __restrict__ x, const float* __restrict__ W1,
                                               const float* __restrict__ dinv, unsigned short* __restrict__ hs1,
                                               int n){
  int lane = threadIdx.x & 63;
  int col = lane & 15;            // A-row / B-col / D-col
  int kg  = lane >> 4;            // k-group (0..3)
  int nt = (n + 15) >> 4;
  short8 B[16];
  #pragma unroll
  for (int t = 0; t < 16; ++t){
    unsigned short o[8];
    #pragma unroll
    for (int e = 0; e < 8; ++e)
      o[e] = f2bf(W1[(t * 32 + kg * 8 + e) * HDIM + col]);
    __builtin_memcpy(&B[t], o, 16);
  }
  int nw = gridDim.x * 4;
  for (int wid = blockIdx.x * 4 + (threadIdx.x >> 6); wid < nt; wid += nw){
    int row = wid * 16 + col;
    const float* xr = x + (size_t)min(row, n - 1) * F_IN;
    floatx4 acc = {0.f, 0.f, 0.f, 0.f};
    #pragma unroll
    for (int t = 0; t < 16; ++t){
      const float4* p = (const float4*)(xr + t * 32 + kg * 8);
      float4 u0 = p[0];
      float4 u1 = p[1];
      acc = __builtin_amdgcn_mfma_f32_16x16x32_bf16(pack8(u0, u1), B[t], acc, 0, 0, 0);
    }
    #pragma unroll
    for (int r = 0; r < 4; ++r){
      int orow = wid * 16 + kg * 4 + r;
      if (orow < n) hs1[(size_t)orow * HDIM + col] = f2bf(dinv[orow] * acc[r]);
    }
  }
}

// ---- conv1 aggregate + b1 + relu + @W2 + dinv scale -> hs2 bf16 [N][8]
// wave per node; 2 lanes per edge (each lane: uint4 = 8 bf16 = half hs1 row).
__global__ __launch_bounds__(256) void k_agg1(const unsigned short* __restrict__ hs1,
    const int* __restrict__ rowptr, const int* __restrict__ ssrc,
    const float* __restrict__ dinv, const float* __restrict__ b1,
    const float* __restrict__ W2, unsigned short* __restrict__ hs2, int n){
  int lane = threadIdx.x & 63;
  int i = blockIdx.x * 4 + (threadIdx.x >> 6);
  if (i >= n) return;
  int slot = lane >> 1, half = lane & 1;
  int beg = rowptr[i], end = rowptr[i + 1];
  const uint4* hv = (const uint4*)hs1;                 // row = 2 uint4
  float acc[8];
  #pragma unroll
  for (int k = 0; k < 8; ++k) acc[k] = 0.f;
  for (int e = beg + slot; e < end; e += 32){
    int src = ssrc[e];
    uint4 v = hv[(size_t)src * 2 + half];
    acc[0] += ulo(v.x); acc[1] += uhi(v.x);
    acc[2] += ulo(v.y); acc[3] += uhi(v.y);
    acc[4] += ulo(v.z); acc[5] += uhi(v.z);
    acc[6] += ulo(v.w); acc[7] += uhi(v.w);
  }
  #pragma unroll
  for (int off = 2; off < 64; off <<= 1){
    #pragma unroll
    for (int k = 0; k < 8; ++k) acc[k] += __shfl_xor(acc[k], off);
  }
  uint4 sv = hv[(size_t)i * 2 + half];
  float self[8] = {ulo(sv.x), uhi(sv.x), ulo(sv.y), uhi(sv.y),
                   ulo(sv.z), uhi(sv.z), ulo(sv.w), uhi(sv.w)};
  float dv = dinv[i];
  const float4* b1v = (const float4*)b1;
  float4 bl = b1v[half * 2], bh = b1v[half * 2 + 1];
  float r[8];
  r[0] = fmaxf(fmaf(dv, acc[0] + self[0], bl.x), 0.f);
  r[1] = fmaxf(fmaf(dv, acc[1] + self[1], bl.y), 0.f);
  r[2] = fmaxf(fmaf(dv, acc[2] + self[2], bl.z), 0.f);
  r[3] = fmaxf(fmaf(dv, acc[3] + self[3], bl.w), 0.f);
  r[4] = fmaxf(fmaf(dv, acc[4] + self[4], bh.x), 0.f);
  r[5] = fmaxf(fmaf(dv, acc[5] + self[5], bh.y), 0.f);
  r[6] = fmaxf(fmaf(dv, acc[6] + self[6], bh.z), 0.f);
  r[7] = fmaxf(fmaf(dv, acc[7] + self[7], bh.w), 0.f);
  const float* w2 = W2 + half * 8 * CDIM;
  float p[CDIM];
  #pragma unroll
  for (int c = 0; c < CDIM; ++c){
    float s = 0.f;
    #pragma unroll
    for (int k = 0; k < 8; ++k) s = fmaf(r[k], w2[k * CDIM + c], s);
    p[c] = s;
  }
  #pragma unroll
  for (int c = 0; c < CDIM; ++c) p[c] += __shfl_xor(p[c], 1);
  if (lane == 0){
    unsigned short o[8];
    #pragma unroll
    for (int c = 0; c < CDIM; ++c) o[c] = f2bf(dv * p[c]);
    o[5] = 0; o[6] = 0; o[7] = 0;
    uint4 v; __builtin_memcpy(&v, o, 16);
    *(uint4*)(hs2 + (size_t)i * 8) = v;
  }
}

// ---- conv2 aggregate + b2 + mlp + log_softmax -> out [N][5] f32
// wave per node; 1 lane per edge (uint4 = full hs2 row).
__global__ __launch_bounds__(256) void k_agg2(const unsigned short* __restrict__ hs2,
    const int* __restrict__ rowptr, const int* __restrict__ ssrc,
    const float* __restrict__ dinv, const float* __restrict__ b2,
    const float* __restrict__ W3, const float* __restrict__ b3,
    const float* __restrict__ W4, const float* __restrict__ b4,
    float* __restrict__ out, int n){
  int lane = threadIdx.x & 63;
  int i = blockIdx.x * 4 + (threadIdx.x >> 6);
  if (i >= n) return;
  int beg = rowptr[i], end = rowptr[i + 1];
  const uint4* hv = (const uint4*)hs2;                 // row = 1 uint4
  float acc[CDIM];
  #pragma unroll
  for (int k = 0; k < CDIM; ++k) acc[k] = 0.f;
  for (int e = beg + lane; e < end; e += 64){
    int src = ssrc[e];
    uint4 v = hv[src];
    acc[0] += ulo(v.x); acc[1] += uhi(v.x);
    acc[2] += ulo(v.y); acc[3] += uhi(v.y);
    acc[4] += ulo(v.z);
  }
  #pragma unroll
  for (int off = 1; off < 64; off <<= 1){
    #pragma unroll
    for (int k = 0; k < CDIM; ++k) acc[k] += __shfl_xor(acc[k], off);
  }
  float dv = dinv[i];
  uint4 sv = hv[i];
  float a0 = fmaf(dv, acc[0] + ulo(sv.x), b2[0]);
  float a1 = fmaf(dv, acc[1] + uhi(sv.x), b2[1]);
  float a2 = fmaf(dv, acc[2] + ulo(sv.y), b2[2]);
  float a3 = fmaf(dv, acc[3] + uhi(sv.y), b2[3]);
  float a4 = fmaf(dv, acc[4] + ulo(sv.z), b2[4]);
  int m = lane & 31;
  float h3 = b3[m];
  h3 = fmaf(a0, W3[0 * 32 + m], h3);
  h3 = fmaf(a1, W3[1 * 32 + m], h3);
  h3 = fmaf(a2, W3[2 * 32 + m], h3);
  h3 = fmaf(a3, W3[3 * 32 + m], h3);
  h3 = fmaf(a4, W3[4 * 32 + m], h3);
  h3 = fmaxf(h3, 0.f);
  float q0 = h3 * W4[m * CDIM + 0], q1 = h3 * W4[m * CDIM + 1], q2 = h3 * W4[m * CDIM + 2];
  float q3 = h3 * W4[m * CDIM + 3], q4 = h3 * W4[m * CDIM + 4];
  #pragma unroll
  for (int off = 1; off < 32; off <<= 1){
    q0 += __shfl_xor(q0, off); q1 += __shfl_xor(q1, off); q2 += __shfl_xor(q2, off);
    q3 += __shfl_xor(q3, off); q4 += __shfl_xor(q4, off);
  }
  q0 += b4[0]; q1 += b4[1]; q2 += b4[2]; q3 += b4[3]; q4 += b4[4];
  float mx = fmaxf(fmaxf(fmaxf(q0, q1), fmaxf(q2, q3)), q4);
  float sum = expf(q0 - mx) + expf(q1 - mx) + expf(q2 - mx) + expf(q3 - mx) + expf(q4 - mx);
  float lse = mx + logf(sum);
  if (lane < CDIM){
    float v = q0;
    if (lane == 1) v = q1;
    if (lane == 2) v = q2;
    if (lane == 3) v = q3;
    if (lane == 4) v = q4;
    out[(size_t)i * CDIM + lane] = v - lse;
  }
}

extern "C" void kernel_launch(void* const* d_in, const int* in_sizes, int n_in,
                              void* d_out, int out_size, void* d_ws, size_t ws_size,
                              hipStream_t stream){
  const float* x  = (const float*)d_in[0];
  const int*   ei = (const int*)d_in[1];
  const float* W1 = (const float*)d_in[2];
  const float* b1 = (const float*)d_in[3];
  const float* W2 = (const float*)d_in[4];
  const float* b2 = (const float*)d_in[5];
  const float* W3 = (const float*)d_in[6];
  const float* b3 = (const float*)d_in[7];
  const float* W4 = (const float*)d_in[8];
  const float* b4 = (const float*)d_in[9];
  float* out = (float*)d_out;

  int N = in_sizes[0] / F_IN;
  int E = in_sizes[1] / 2;
  int NPB = (N + NB - 1) / NB;      // nodes per bucket (98 for N=100000)

  char* ws = (char*)d_ws;
  size_t off = 0;
  auto alloc = [&](size_t bytes) -> char* {
    char* p = ws + off;
    off += (bytes + 255) & ~(size_t)255;
    return p;
  };
  int* flag  = (int*)alloc(4);
  int* gwp   = (int*)alloc((size_t)NB * GWP_STRIDE * 4);
  int* bbase = (int*)alloc(((size_t)NB + 1) * 4);
  int* rowptr= (int*)alloc(((size_t)N + 1) * 4);
  float* dinv= (float*)alloc((size_t)N * 4);
  int* pairs = (int*)alloc((size_t)NB * SEG * 4);   // segmented, 32 MB
  int* ssrc  = (int*)alloc((size_t)E * 4);
  unsigned short* hs1 = (unsigned short*)alloc((size_t)N * HDIM * 2);
  unsigned short* hs2 = (unsigned short*)alloc((size_t)N * 8 * 2);
  (void)ws_size; (void)n_in; (void)out_size;

  hipMemsetAsync(flag, 0, 4, stream);
  k_detect<<<8, 256, 0, stream>>>(ei, flag, gwp, E);
  int sblocks = (E + SCHUNK - 1) / SCHUNK;
  k_binscatter<<<sblocks, 1024, 0, stream>>>(ei, flag, gwp, pairs, E, NPB);
  k_scanNB<<<1, 1024, 0, stream>>>(gwp, bbase, NB);
  k_bucket<<<NB, 512, 0, stream>>>(pairs, bbase, rowptr, dinv, ssrc, NPB, N, E);
  k_gemm1<<<768, 256, 0, stream>>>(x, W1, dinv, hs1, N);
  k_agg1<<<(N + 3) / 4, 256, 0, stream>>>(hs1, rowptr, ssrc, dinv, b1, W2, hs2, N);
  k_agg2<<<(N + 3) / 4, 256, 0, stream>>>(hs2, rowptr, ssrc, dinv, b2, W3, b3, W4, b4, out, N);
}

// Round 8
// 273.825 us; speedup vs baseline: 4.5694x; 1.0309x over previous
//
#include <hip/hip_runtime.h>
#include <hip/hip_bf16.h>

// GCN: conv1(512->16) + relu + conv2(16->5) + mlp(5->32->5) + log_softmax
// out[dst] = dinv[dst]*(sum_{src in N(dst)} hs[src] + hs[dst]) + b,  hs = dinv*(h@W)
// CSR build: segmented 2-level bucket sort, single edge-stream pass (reg-held):
//   detect(+init) -> binscatter(reg counting-sort) -> scanNB -> bucket(compact)
// gemm1 via MFMA with W1 register-resident B-frags, multi-tile per wave.

#define F_IN 512
#define HDIM 16
#define CDIM 5
#define NB   1024      // dst-range buckets
#define SEG  8192      // per-bucket segment capacity in pairs[] (mean load 6250, 24 sigma)
#define GWP_STRIDE 16  // pad gwp counters to one per 64B line
#define EPT  12        // edges per thread in binscatter
#define SCHUNK (1024*EPT)
#define CAP  8192      // per-bucket LDS staging in k_bucket (ints)

typedef __attribute__((ext_vector_type(8))) short short8;
typedef __attribute__((ext_vector_type(4))) float floatx4;

__device__ inline float bf2f(unsigned short u){
  unsigned int i = ((unsigned int)u) << 16; float f; __builtin_memcpy(&f, &i, 4); return f;
}
__device__ inline unsigned short f2bf(float x){
  unsigned int i; __builtin_memcpy(&i, &x, 4);
  unsigned int r = i + 0x7FFFu + ((i >> 16) & 1u);
  return (unsigned short)(r >> 16);
}
__device__ inline float ulo(unsigned int u){
  unsigned int v = u << 16; float f; __builtin_memcpy(&f, &v, 4); return f;
}
__device__ inline float uhi(unsigned int u){
  unsigned int v = u & 0xFFFF0000u; float f; __builtin_memcpy(&f, &v, 4); return f;
}
__device__ inline short8 pack8(float4 u0, float4 u1){
  unsigned short o[8] = {f2bf(u0.x), f2bf(u0.y), f2bf(u0.z), f2bf(u0.w),
                         f2bf(u1.x), f2bf(u1.y), f2bf(u1.z), f2bf(u1.w)};
  short8 r; __builtin_memcpy(&r, o, 16); return r;
}

// ---- single block: init flag + gwp segment bases + detect int64/int32 layout
__global__ __launch_bounds__(1024) void k_detect(const int* __restrict__ ei, int* __restrict__ flag,
                                                 int* __restrict__ gwp, int E){
  int t = threadIdx.x;
  if (t == 0) *flag = 0;
  gwp[t * GWP_STRIDE] = t * SEG;          // 1024 threads == NB
  __syncthreads();
  long long step = E / 1024; if (step < 1) step = 1;
  long long pos = 2LL * ((long long)t * step) + 1;
  if (pos < 2LL * E){
    if (ei[pos] != 0) atomicOr(flag, 1);  // nonzero odd word => int32
  }
}

// ---- block-local counting sort, edges held in registers (single stream pass)
__global__ __launch_bounds__(1024) void k_binscatter(const int* __restrict__ ei, const int* __restrict__ flag,
                                                     int* __restrict__ gwp, int* __restrict__ pairs,
                                                     int E, int NPB){
  __shared__ int bh[NB];          // hist, then local write-ptr
  __shared__ int lex[NB + 1];     // local exclusive scan
  __shared__ int bb2[NB];         // reserved global base per bucket
  __shared__ int wsum[16];
  __shared__ int stage[SCHUNK];
  int t = threadIdx.x;
  int e0 = blockIdx.x * SCHUNK;
  int e1 = min(E, e0 + SCHUNK);
  int cnt = e1 - e0;
  if (cnt <= 0) return;
  int is32 = *flag;
  const uint2* ei2 = (const uint2*)ei;
  // load this thread's edges once into registers
  int pk[EPT]; int bi[EPT];
  #pragma unroll
  for (int j = 0; j < EPT; ++j){
    int e = e0 + t + j * 1024;
    if (e < e1){
      int src, dst;
      if (is32){ src = ei[e]; dst = ei[(size_t)E + e]; }
      else     { src = (int)ei2[e].x; dst = (int)ei2[(size_t)E + e].x; }
      int b = dst / NPB;
      pk[j] = src | ((dst - b * NPB) << 20);
      bi[j] = b;
    } else bi[j] = -1;
  }
  bh[t] = 0;
  __syncthreads();
  // A: local hist from regs
  #pragma unroll
  for (int j = 0; j < EPT; ++j) if (bi[j] >= 0) atomicAdd(&bh[bi[j]], 1);
  __syncthreads();
  // B: block scan (t == bucket), reserve global run in the bucket's segment
  {
    int lane = t & 63, w = t >> 6;
    int v = bh[t];
    int xs = v;
    #pragma unroll
    for (int off = 1; off < 64; off <<= 1){
      int y = __shfl_up(xs, off);
      if (lane >= off) xs += y;
    }
    if (lane == 63) wsum[w] = xs;
    __syncthreads();
    int woff = 0;
    for (int k = 0; k < w; ++k) woff += wsum[k];
    int excl = woff + xs - v;
    lex[t] = excl;
    if (t == 1023) lex[NB] = woff + xs;
    bb2[t] = v ? atomicAdd(&gwp[t * GWP_STRIDE], v) : 0;
    __syncthreads();              // all reads of bh done before overwrite
    bh[t] = excl;                 // becomes local write ptr
  }
  __syncthreads();
  // C: scatter into LDS stage from regs (packed src | dl<<20)
  #pragma unroll
  for (int j = 0; j < EPT; ++j){
    if (bi[j] >= 0){
      int idx = atomicAdd(&bh[bi[j]], 1);
      stage[idx] = pk[j];
    }
  }
  __syncthreads();
  // D: coalesced copy-out (consecutive k -> consecutive addresses within a run)
  for (int k = t; k < cnt; k += 1024){
    int lo = 0, hi = NB;          // largest b with lex[b] <= k
    while (hi - lo > 1){
      int mid = (lo + hi) >> 1;
      if (lex[mid] <= k) lo = mid; else hi = mid;
    }
    pairs[bb2[lo] + (k - lex[lo])] = stage[k];
  }
}

// ---- compact scan over buckets: count = gwp_final - segment base
__global__ __launch_bounds__(1024) void k_scanNB(const int* __restrict__ gwp, int* __restrict__ bbase,
                                                 int nb){
  __shared__ int wsum[16];
  int t = threadIdx.x, lane = t & 63, w = t >> 6;
  int v = (t < nb) ? (gwp[t * GWP_STRIDE] - t * SEG) : 0;
  int xs = v;
  #pragma unroll
  for (int off = 1; off < 64; off <<= 1){
    int y = __shfl_up(xs, off);
    if (lane >= off) xs += y;
  }
  if (lane == 63) wsum[w] = xs;
  __syncthreads();
  int woff = 0;
  for (int k = 0; k < w; ++k) woff += wsum[k];
  if (t < nb) bbase[t] = woff + xs - v;
  if (t == 1023) bbase[nb] = woff + xs;
}

// ---- per-bucket CSR finalize: 4-way sub-hist, shfl scan, LDS sort, coalesced flush
__global__ __launch_bounds__(512) void k_bucket(const int* __restrict__ pairs, const int* __restrict__ bbase,
                                                int* __restrict__ rowptr, float* __restrict__ dinv,
                                                int* __restrict__ ssrc, int NPB, int n, int Etot){
  __shared__ int lcnt[4][128];    // sub-hists, then sub-write-ptrs
  __shared__ int tot[128];
  __shared__ int lexcl[128];
  __shared__ int w0sum;
  __shared__ int stage[CAP];
  int b = blockIdx.x;
  int t = threadIdx.x;
  int g = t >> 7;                 // 4 groups of 128 threads
  int node0 = b * NPB;
  int pbase = b * SEG;
  int obase = bbase[b];
  int cntE = bbase[b + 1] - obase;
  lcnt[g][t & 127] = 0;
  __syncthreads();
  for (int k = t; k < cntE; k += 512){
    unsigned int v = (unsigned int)pairs[pbase + k];
    atomicAdd(&lcnt[g][v >> 20], 1);
  }
  __syncthreads();
  if (t < 128){
    int s0 = lcnt[0][t], s1 = lcnt[1][t], s2 = lcnt[2][t], s3 = lcnt[3][t];
    tot[t] = s0 + s1 + s2 + s3;
    lcnt[0][t] = 0; lcnt[1][t] = s0; lcnt[2][t] = s0 + s1; lcnt[3][t] = s0 + s1 + s2;
  }
  __syncthreads();
  // exclusive scan over tot[0..127] (threads 0..127, 2 waves + carry)
  int lane = t & 63;
  int v = (t < 128) ? tot[t] : 0;
  int xs = v;
  #pragma unroll
  for (int off = 1; off < 64; off <<= 1){
    int y = __shfl_up(xs, off);
    if (lane >= off) xs += y;
  }
  if (t == 63) w0sum = xs;
  __syncthreads();
  if (t < 128) lexcl[t] = xs - v + ((t >= 64) ? w0sum : 0);
  __syncthreads();
  if (t < NPB){
    int node = node0 + t;
    if (node < n){
      rowptr[node] = obase + lexcl[t];
      dinv[node] = rsqrtf((float)(tot[t] + 1));            // +1 self loop
    }
  }
  lcnt[g][t & 127] += lexcl[t & 127];                      // sub-write-ptr
  if (b == 0 && t == 0) rowptr[n] = Etot;
  __syncthreads();
  for (int k = t; k < cntE; k += 512){
    unsigned int v2 = (unsigned int)pairs[pbase + k];
    int idx = atomicAdd(&lcnt[g][v2 >> 20], 1);
    int src = (int)(v2 & 0xFFFFFu);
    if (idx < CAP) stage[idx] = src;
    else ssrc[obase + idx] = src;
  }
  __syncthreads();
  int m = cntE < CAP ? cntE : CAP;
  for (int k = t; k < m; k += 512) ssrc[obase + k] = stage[k];
}

// ---- hs1 = dinv * (x @ W1) via MFMA 16x16x32 bf16, multi-tile per wave.
__global__ __launch_bounds__(256) void k_gemm1(const float* __restrict__ x, const float* __restrict__ W1,
                                               const float* __restrict__ dinv, unsigned short* __restrict__ hs1,
                                               int n){
  int lane = threadIdx.x & 63;
  int col = lane & 15;            // A-row / B-col / D-col
  int kg  = lane >> 4;            // k-group (0..3)
  int nt = (n + 15) >> 4;
  short8 B[16];
  #pragma unroll
  for (int t = 0; t < 16; ++t){
    unsigned short o[8];
    #pragma unroll
    for (int e = 0; e < 8; ++e)
      o[e] = f2bf(W1[(t * 32 + kg * 8 + e) * HDIM + col]);
    __builtin_memcpy(&B[t], o, 16);
  }
  int nw = gridDim.x * 4;
  for (int wid = blockIdx.x * 4 + (threadIdx.x >> 6); wid < nt; wid += nw){
    int row = wid * 16 + col;
    const float* xr = x + (size_t)min(row, n - 1) * F_IN;
    floatx4 acc = {0.f, 0.f, 0.f, 0.f};
    #pragma unroll
    for (int t = 0; t < 16; ++t){
      const float4* p = (const float4*)(xr + t * 32 + kg * 8);
      float4 u0 = p[0];
      float4 u1 = p[1];
      acc = __builtin_amdgcn_mfma_f32_16x16x32_bf16(pack8(u0, u1), B[t], acc, 0, 0, 0);
    }
    #pragma unroll
    for (int r = 0; r < 4; ++r){
      int orow = wid * 16 + kg * 4 + r;
      if (orow < n) hs1[(size_t)orow * HDIM + col] = f2bf(dinv[orow] * acc[r]);
    }
  }
}

// ---- conv1 aggregate + b1 + relu + @W2 + dinv scale -> hs2 bf16 [N][8]
__global__ __launch_bounds__(256) void k_agg1(const unsigned short* __restrict__ hs1,
    const int* __restrict__ rowptr, const int* __restrict__ ssrc,
    const float* __restrict__ dinv, const float* __restrict__ b1,
    const float* __restrict__ W2, unsigned short* __restrict__ hs2, int n){
  int lane = threadIdx.x & 63;
  int i = blockIdx.x * 4 + (threadIdx.x >> 6);
  if (i >= n) return;
  int slot = lane >> 1, half = lane & 1;
  int beg = rowptr[i], end = rowptr[i + 1];
  const uint4* hv = (const uint4*)hs1;                 // row = 2 uint4
  float acc[8];
  #pragma unroll
  for (int k = 0; k < 8; ++k) acc[k] = 0.f;
  for (int e = beg + slot; e < end; e += 32){
    int src = ssrc[e];
    uint4 v = hv[(size_t)src * 2 + half];
    acc[0] += ulo(v.x); acc[1] += uhi(v.x);
    acc[2] += ulo(v.y); acc[3] += uhi(v.y);
    acc[4] += ulo(v.z); acc[5] += uhi(v.z);
    acc[6] += ulo(v.w); acc[7] += uhi(v.w);
  }
  #pragma unroll
  for (int off = 2; off < 64; off <<= 1){
    #pragma unroll
    for (int k = 0; k < 8; ++k) acc[k] += __shfl_xor(acc[k], off);
  }
  uint4 sv = hv[(size_t)i * 2 + half];
  float self[8] = {ulo(sv.x), uhi(sv.x), ulo(sv.y), uhi(sv.y),
                   ulo(sv.z), uhi(sv.z), ulo(sv.w), uhi(sv.w)};
  float dv = dinv[i];
  const float4* b1v = (const float4*)b1;
  float4 bl = b1v[half * 2], bh = b1v[half * 2 + 1];
  float r[8];
  r[0] = fmaxf(fmaf(dv, acc[0] + self[0], bl.x), 0.f);
  r[1] = fmaxf(fmaf(dv, acc[1] + self[1], bl.y), 0.f);
  r[2] = fmaxf(fmaf(dv, acc[2] + self[2], bl.z), 0.f);
  r[3] = fmaxf(fmaf(dv, acc[3] + self[3], bl.w), 0.f);
  r[4] = fmaxf(fmaf(dv, acc[4] + self[4], bh.x), 0.f);
  r[5] = fmaxf(fmaf(dv, acc[5] + self[5], bh.y), 0.f);
  r[6] = fmaxf(fmaf(dv, acc[6] + self[6], bh.z), 0.f);
  r[7] = fmaxf(fmaf(dv, acc[7] + self[7], bh.w), 0.f);
  const float* w2 = W2 + half * 8 * CDIM;
  float p[CDIM];
  #pragma unroll
  for (int c = 0; c < CDIM; ++c){
    float s = 0.f;
    #pragma unroll
    for (int k = 0; k < 8; ++k) s = fmaf(r[k], w2[k * CDIM + c], s);
    p[c] = s;
  }
  #pragma unroll
  for (int c = 0; c < CDIM; ++c) p[c] += __shfl_xor(p[c], 1);
  if (lane == 0){
    unsigned short o[8];
    #pragma unroll
    for (int c = 0; c < CDIM; ++c) o[c] = f2bf(dv * p[c]);
    o[5] = 0; o[6] = 0; o[7] = 0;
    uint4 v; __builtin_memcpy(&v, o, 16);
    *(uint4*)(hs2 + (size_t)i * 8) = v;
  }
}

// ---- conv2 aggregate + b2 + mlp + log_softmax -> out [N][5] f32
__global__ __launch_bounds__(256) void k_agg2(const unsigned short* __restrict__ hs2,
    const int* __restrict__ rowptr, const int* __restrict__ ssrc,
    const float* __restrict__ dinv, const float* __restrict__ b2,
    const float* __restrict__ W3, const float* __restrict__ b3,
    const float* __restrict__ W4, const float* __restrict__ b4,
    float* __restrict__ out, int n){
  int lane = threadIdx.x & 63;
  int i = blockIdx.x * 4 + (threadIdx.x >> 6);
  if (i >= n) return;
  int beg = rowptr[i], end = rowptr[i + 1];
  const uint4* hv = (const uint4*)hs2;                 // row = 1 uint4
  float acc[CDIM];
  #pragma unroll
  for (int k = 0; k < CDIM; ++k) acc[k] = 0.f;
  for (int e = beg + lane; e < end; e += 64){
    int src = ssrc[e];
    uint4 v = hv[src];
    acc[0] += ulo(v.x); acc[1] += uhi(v.x);
    acc[2] += ulo(v.y); acc[3] += uhi(v.y);
    acc[4] += ulo(v.z);
  }
  #pragma unroll
  for (int off = 1; off < 64; off <<= 1){
    #pragma unroll
    for (int k = 0; k < CDIM; ++k) acc[k] += __shfl_xor(acc[k], off);
  }
  float dv = dinv[i];
  uint4 sv = hv[i];
  float a0 = fmaf(dv, acc[0] + ulo(sv.x), b2[0]);
  float a1 = fmaf(dv, acc[1] + uhi(sv.x), b2[1]);
  float a2 = fmaf(dv, acc[2] + ulo(sv.y), b2[2]);
  float a3 = fmaf(dv, acc[3] + uhi(sv.y), b2[3]);
  float a4 = fmaf(dv, acc[4] + ulo(sv.z), b2[4]);
  int m = lane & 31;
  float h3 = b3[m];
  h3 = fmaf(a0, W3[0 * 32 + m], h3);
  h3 = fmaf(a1, W3[1 * 32 + m], h3);
  h3 = fmaf(a2, W3[2 * 32 + m], h3);
  h3 = fmaf(a3, W3[3 * 32 + m], h3);
  h3 = fmaf(a4, W3[4 * 32 + m], h3);
  h3 = fmaxf(h3, 0.f);
  float q0 = h3 * W4[m * CDIM + 0], q1 = h3 * W4[m * CDIM + 1], q2 = h3 * W4[m * CDIM + 2];
  float q3 = h3 * W4[m * CDIM + 3], q4 = h3 * W4[m * CDIM + 4];
  #pragma unroll
  for (int off = 1; off < 32; off <<= 1){
    q0 += __shfl_xor(q0, off); q1 += __shfl_xor(q1, off); q2 += __shfl_xor(q2, off);
    q3 += __shfl_xor(q3, off); q4 += __shfl_xor(q4, off);
  }
  q0 += b4[0]; q1 += b4[1]; q2 += b4[2]; q3 += b4[3]; q4 += b4[4];
  float mx = fmaxf(fmaxf(fmaxf(q0, q1), fmaxf(q2, q3)), q4);
  float sum = expf(q0 - mx) + expf(q1 - mx) + expf(q2 - mx) + expf(q3 - mx) + expf(q4 - mx);
  float lse = mx + logf(sum);
  if (lane < CDIM){
    float v = q0;
    if (lane == 1) v = q1;
    if (lane == 2) v = q2;
    if (lane == 3) v = q3;
    if (lane == 4) v = q4;
    out[(size_t)i * CDIM + lane] = v - lse;
  }
}

extern "C" void kernel_launch(void* const* d_in, const int* in_sizes, int n_in,
                              void* d_out, int out_size, void* d_ws, size_t ws_size,
                              hipStream_t stream){
  const float* x  = (const float*)d_in[0];
  const int*   ei = (const int*)d_in[1];
  const float* W1 = (const float*)d_in[2];
  const float* b1 = (const float*)d_in[3];
  const float* W2 = (const float*)d_in[4];
  const float* b2 = (const float*)d_in[5];
  const float* W3 = (const float*)d_in[6];
  const float* b3 = (const float*)d_in[7];
  const float* W4 = (const float*)d_in[8];
  const float* b4 = (const float*)d_in[9];
  float* out = (float*)d_out;

  int N = in_sizes[0] / F_IN;
  int E = in_sizes[1] / 2;
  int NPB = (N + NB - 1) / NB;      // nodes per bucket (98 for N=100000)

  char* ws = (char*)d_ws;
  size_t off = 0;
  auto alloc = [&](size_t bytes) -> char* {
    char* p = ws + off;
    off += (bytes + 255) & ~(size_t)255;
    return p;
  };
  int* flag  = (int*)alloc(4);
  int* gwp   = (int*)alloc((size_t)NB * GWP_STRIDE * 4);
  int* bbase = (int*)alloc(((size_t)NB + 1) * 4);
  int* rowptr= (int*)alloc(((size_t)N + 1) * 4);
  float* dinv= (float*)alloc((size_t)N * 4);
  int* pairs = (int*)alloc((size_t)NB * SEG * 4);   // segmented, 32 MB
  int* ssrc  = (int*)alloc((size_t)E * 4);
  unsigned short* hs1 = (unsigned short*)alloc((size_t)N * HDIM * 2);
  unsigned short* hs2 = (unsigned short*)alloc((size_t)N * 8 * 2);
  (void)ws_size; (void)n_in; (void)out_size;

  k_detect<<<1, 1024, 0, stream>>>(ei, flag, gwp, E);
  int sblocks = (E + SCHUNK - 1) / SCHUNK;
  k_binscatter<<<sblocks, 1024, 0, stream>>>(ei, flag, gwp, pairs, E, NPB);
  k_scanNB<<<1, 1024, 0, stream>>>(gwp, bbase, NB);
  k_bucket<<<NB, 512, 0, stream>>>(pairs, bbase, rowptr, dinv, ssrc, NPB, N, E);
  k_gemm1<<<768, 256, 0, stream>>>(x, W1, dinv, hs1, N);
  k_agg1<<<(N + 3) / 4, 256, 0, stream>>>(hs1, rowptr, ssrc, dinv, b1, W2, hs2, N);
  k_agg2<<<(N + 3) / 4, 256, 0, stream>>>(hs2, rowptr, ssrc, dinv, b2, W3, b3, W4, b4, out, N);
}

// Round 9
// 265.376 us; speedup vs baseline: 4.7149x; 1.0318x over previous
//
#include <hip/hip_runtime.h>
#include <hip/hip_bf16.h>

// GCN: conv1(512->16) + relu + conv2(16->5) + mlp(5->32->5) + log_softmax
// out[dst] = dinv[dst]*(sum_{src in N(dst)} hs[src] + hs[dst]) + b,  hs = dinv*(h@W)
// CSR build: segmented 2-level bucket sort, single edge pass, k->bucket LDS map
// (no binary search). gemm1 via MFMA with pre-packed register-resident W1.

#define F_IN 512
#define HDIM 16
#define CDIM 5
#define NB   1024      // dst-range buckets
#define SEG  8192      // per-bucket segment capacity in pairs[] (mean 6250, 24 sigma)
#define GWP_STRIDE 16  // pad gwp counters to one per 64B line
#define EPT  10        // edges per thread in binscatter
#define SCHUNK (1024*EPT)
#define CAP  8192      // per-bucket LDS staging in k_bucket (ints)

typedef __attribute__((ext_vector_type(8))) short short8;
typedef __attribute__((ext_vector_type(4))) float floatx4;

__device__ inline float bf2f(unsigned short u){
  unsigned int i = ((unsigned int)u) << 16; float f; __builtin_memcpy(&f, &i, 4); return f;
}
__device__ inline unsigned short f2bf(float x){
  unsigned int i; __builtin_memcpy(&i, &x, 4);
  unsigned int r = i + 0x7FFFu + ((i >> 16) & 1u);
  return (unsigned short)(r >> 16);
}
__device__ inline float ulo(unsigned int u){
  unsigned int v = u << 16; float f; __builtin_memcpy(&f, &v, 4); return f;
}
__device__ inline float uhi(unsigned int u){
  unsigned int v = u & 0xFFFF0000u; float f; __builtin_memcpy(&f, &v, 4); return f;
}
__device__ inline short8 pack8(float4 u0, float4 u1){
  unsigned short o[8] = {f2bf(u0.x), f2bf(u0.y), f2bf(u0.z), f2bf(u0.w),
                         f2bf(u1.x), f2bf(u1.y), f2bf(u1.z), f2bf(u1.w)};
  short8 r; __builtin_memcpy(&r, o, 16); return r;
}

// ---- single block: init flag + gwp segment bases + detect int64/int32 layout
__global__ __launch_bounds__(1024) void k_detect(const int* __restrict__ ei, int* __restrict__ flag,
                                                 int* __restrict__ gwp, int E){
  int t = threadIdx.x;
  if (t == 0) *flag = 0;
  gwp[t * GWP_STRIDE] = t * SEG;          // 1024 threads == NB
  __syncthreads();
  long long step = E / 1024; if (step < 1) step = 1;
  long long pos = 2LL * ((long long)t * step) + 1;
  if (pos < 2LL * E){
    if (ei[pos] != 0) atomicOr(flag, 1);  // nonzero odd word => int32
  }
}

// ---- pre-pack W1 into MFMA B-frag layout: pw[t][kg][col] = short8 of
//      bf16(W1[(t*32+kg*8+e)*16+col]), e=0..7
__global__ __launch_bounds__(256) void k_packW1(const float* __restrict__ W1,
                                                unsigned short* __restrict__ pw){
  int s = threadIdx.x;                    // 256 threads, 4 slots each
  for (int slot = s; slot < 1024; slot += 256){
    int col = slot & 15, kg = (slot >> 4) & 3, t = slot >> 6;
    unsigned short o[8];
    #pragma unroll
    for (int e = 0; e < 8; ++e)
      o[e] = f2bf(W1[(t * 32 + kg * 8 + e) * HDIM + col]);
    uint4 v; __builtin_memcpy(&v, o, 16);
    *(uint4*)(pw + (size_t)slot * 8) = v;
  }
}

// ---- block-local counting sort, edges in regs, k->bucket LDS map (no search)
__global__ __launch_bounds__(1024) void k_binscatter(const int* __restrict__ ei, const int* __restrict__ flag,
                                                     int* __restrict__ gwp, int* __restrict__ pairs,
                                                     int E, int NPB){
  __shared__ int bh[NB];              // hist, then local write-ptr
  __shared__ int lex[NB + 1];         // local exclusive scan
  __shared__ int bb2[NB];             // reserved global base per bucket
  __shared__ int wsum[16];
  __shared__ unsigned short kb[SCHUNK];  // k -> bucket map
  __shared__ int stage[SCHUNK];
  int t = threadIdx.x;
  int e0 = blockIdx.x * SCHUNK;
  int e1 = min(E, e0 + SCHUNK);
  int cnt = e1 - e0;
  if (cnt <= 0) return;
  int is32 = *flag;
  const uint2* ei2 = (const uint2*)ei;
  // load this thread's edges once into registers
  int pk[EPT]; int bi[EPT];
  #pragma unroll
  for (int j = 0; j < EPT; ++j){
    int e = e0 + t + j * 1024;
    if (e < e1){
      int src, dst;
      if (is32){ src = ei[e]; dst = ei[(size_t)E + e]; }
      else     { src = (int)ei2[e].x; dst = (int)ei2[(size_t)E + e].x; }
      int b = dst / NPB;
      pk[j] = src | ((dst - b * NPB) << 20);
      bi[j] = b;
    } else bi[j] = -1;
  }
  bh[t] = 0;
  __syncthreads();
  // A: local hist from regs
  #pragma unroll
  for (int j = 0; j < EPT; ++j) if (bi[j] >= 0) atomicAdd(&bh[bi[j]], 1);
  __syncthreads();
  // B: block scan (t == bucket), reserve global run in the bucket's segment
  {
    int lane = t & 63, w = t >> 6;
    int v = bh[t];
    int xs = v;
    #pragma unroll
    for (int off = 1; off < 64; off <<= 1){
      int y = __shfl_up(xs, off);
      if (lane >= off) xs += y;
    }
    if (lane == 63) wsum[w] = xs;
    __syncthreads();
    int woff = 0;
    for (int k = 0; k < w; ++k) woff += wsum[k];
    int excl = woff + xs - v;
    lex[t] = excl;
    if (t == 1023) lex[NB] = woff + xs;
    bb2[t] = v ? atomicAdd(&gwp[t * GWP_STRIDE], v) : 0;
    __syncthreads();              // all reads of bh done before overwrite
    bh[t] = excl;                 // becomes local write ptr
  }
  __syncthreads();
  // C: scatter into LDS stage from regs; record bucket in kb
  #pragma unroll
  for (int j = 0; j < EPT; ++j){
    if (bi[j] >= 0){
      int idx = atomicAdd(&bh[bi[j]], 1);
      stage[idx] = pk[j];
      kb[idx] = (unsigned short)bi[j];
    }
  }
  __syncthreads();
  // D: coalesced copy-out; bucket comes from kb (no search)
  for (int k = t; k < cnt; k += 1024){
    int b = kb[k];
    pairs[bb2[b] + (k - lex[b])] = stage[k];
  }
}

// ---- compact scan over buckets: count = gwp_final - segment base
__global__ __launch_bounds__(1024) void k_scanNB(const int* __restrict__ gwp, int* __restrict__ bbase,
                                                 int nb){
  __shared__ int wsum[16];
  int t = threadIdx.x, lane = t & 63, w = t >> 6;
  int v = (t < nb) ? (gwp[t * GWP_STRIDE] - t * SEG) : 0;
  int xs = v;
  #pragma unroll
  for (int off = 1; off < 64; off <<= 1){
    int y = __shfl_up(xs, off);
    if (lane >= off) xs += y;
  }
  if (lane == 63) wsum[w] = xs;
  __syncthreads();
  int woff = 0;
  for (int k = 0; k < w; ++k) woff += wsum[k];
  if (t < nb) bbase[t] = woff + xs - v;
  if (t == 1023) bbase[nb] = woff + xs;
}

// ---- per-bucket CSR finalize: 4-way sub-hist, shfl scan, LDS sort, coalesced flush
__global__ __launch_bounds__(512) void k_bucket(const int* __restrict__ pairs, const int* __restrict__ bbase,
                                                int* __restrict__ rowptr, float* __restrict__ dinv,
                                                int* __restrict__ ssrc, int NPB, int n, int Etot){
  __shared__ int lcnt[4][128];    // sub-hists, then sub-write-ptrs
  __shared__ int tot[128];
  __shared__ int lexcl[128];
  __shared__ int w0sum;
  __shared__ int stage[CAP];
  int b = blockIdx.x;
  int t = threadIdx.x;
  int g = t >> 7;                 // 4 groups of 128 threads
  int node0 = b * NPB;
  int pbase = b * SEG;
  int obase = bbase[b];
  int cntE = bbase[b + 1] - obase;
  lcnt[g][t & 127] = 0;
  __syncthreads();
  for (int k = t; k < cntE; k += 512){
    unsigned int v = (unsigned int)pairs[pbase + k];
    atomicAdd(&lcnt[g][v >> 20], 1);
  }
  __syncthreads();
  if (t < 128){
    int s0 = lcnt[0][t], s1 = lcnt[1][t], s2 = lcnt[2][t], s3 = lcnt[3][t];
    tot[t] = s0 + s1 + s2 + s3;
    lcnt[0][t] = 0; lcnt[1][t] = s0; lcnt[2][t] = s0 + s1; lcnt[3][t] = s0 + s1 + s2;
  }
  __syncthreads();
  // exclusive scan over tot[0..127]
  int lane = t & 63;
  int v = (t < 128) ? tot[t] : 0;
  int xs = v;
  #pragma unroll
  for (int off = 1; off < 64; off <<= 1){
    int y = __shfl_up(xs, off);
    if (lane >= off) xs += y;
  }
  if (t == 63) w0sum = xs;
  __syncthreads();
  if (t < 128) lexcl[t] = xs - v + ((t >= 64) ? w0sum : 0);
  __syncthreads();
  if (t < NPB){
    int node = node0 + t;
    if (node < n){
      rowptr[node] = obase + lexcl[t];
      dinv[node] = rsqrtf((float)(tot[t] + 1));            // +1 self loop
    }
  }
  lcnt[g][t & 127] += lexcl[t & 127];                      // sub-write-ptr
  if (b == 0 && t == 0) rowptr[n] = Etot;
  __syncthreads();
  for (int k = t; k < cntE; k += 512){
    unsigned int v2 = (unsigned int)pairs[pbase + k];
    int idx = atomicAdd(&lcnt[g][v2 >> 20], 1);
    int src = (int)(v2 & 0xFFFFFu);
    if (idx < CAP) stage[idx] = src;
    else ssrc[obase + idx] = src;
  }
  __syncthreads();
  int m = cntE < CAP ? cntE : CAP;
  for (int k = t; k < m; k += 512) ssrc[obase + k] = stage[k];
}

// ---- hs1 = dinv * (x @ W1) via MFMA 16x16x32 bf16, multi-tile per wave.
// W1 pre-packed: B[t] is one coalesced 16B load per lane.
__global__ __launch_bounds__(256) void k_gemm1(const float* __restrict__ x, const unsigned short* __restrict__ pw,
                                               const float* __restrict__ dinv, unsigned short* __restrict__ hs1,
                                               int n){
  int lane = threadIdx.x & 63;
  int col = lane & 15;            // A-row / B-col / D-col
  int kg  = lane >> 4;            // k-group (0..3)
  int nt = (n + 15) >> 4;
  const short8* pw8 = (const short8*)pw;
  short8 B[16];
  #pragma unroll
  for (int t = 0; t < 16; ++t) B[t] = pw8[t * 64 + kg * 16 + col];
  int nw = gridDim.x * 4;
  for (int wid = blockIdx.x * 4 + (threadIdx.x >> 6); wid < nt; wid += nw){
    int row = wid * 16 + col;
    const float* xr = x + (size_t)min(row, n - 1) * F_IN;
    floatx4 acc = {0.f, 0.f, 0.f, 0.f};
    #pragma unroll
    for (int t = 0; t < 16; ++t){
      const float4* p = (const float4*)(xr + t * 32 + kg * 8);
      float4 u0 = p[0];
      float4 u1 = p[1];
      acc = __builtin_amdgcn_mfma_f32_16x16x32_bf16(pack8(u0, u1), B[t], acc, 0, 0, 0);
    }
    #pragma unroll
    for (int r = 0; r < 4; ++r){
      int orow = wid * 16 + kg * 4 + r;
      if (orow < n) hs1[(size_t)orow * HDIM + col] = f2bf(dinv[orow] * acc[r]);
    }
  }
}

// ---- conv1 aggregate + b1 + relu + @W2 + dinv scale -> hs2 bf16 [N][8]
__global__ __launch_bounds__(256) void k_agg1(const unsigned short* __restrict__ hs1,
    const int* __restrict__ rowptr, const int* __restrict__ ssrc,
    const float* __restrict__ dinv, const float* __restrict__ b1,
    const float* __restrict__ W2, unsigned short* __restrict__ hs2, int n){
  int lane = threadIdx.x & 63;
  int i = blockIdx.x * 4 + (threadIdx.x >> 6);
  if (i >= n) return;
  int slot = lane >> 1, half = lane & 1;
  int beg = rowptr[i], end = rowptr[i + 1];
  const uint4* hv = (const uint4*)hs1;                 // row = 2 uint4
  float acc[8];
  #pragma unroll
  for (int k = 0; k < 8; ++k) acc[k] = 0.f;
  for (int e = beg + slot; e < end; e += 32){
    int src = ssrc[e];
    uint4 v = hv[(size_t)src * 2 + half];
    acc[0] += ulo(v.x); acc[1] += uhi(v.x);
    acc[2] += ulo(v.y); acc[3] += uhi(v.y);
    acc[4] += ulo(v.z); acc[5] += uhi(v.z);
    acc[6] += ulo(v.w); acc[7] += uhi(v.w);
  }
  #pragma unroll
  for (int off = 2; off < 64; off <<= 1){
    #pragma unroll
    for (int k = 0; k < 8; ++k) acc[k] += __shfl_xor(acc[k], off);
  }
  uint4 sv = hv[(size_t)i * 2 + half];
  float self[8] = {ulo(sv.x), uhi(sv.x), ulo(sv.y), uhi(sv.y),
                   ulo(sv.z), uhi(sv.z), ulo(sv.w), uhi(sv.w)};
  float dv = dinv[i];
  const float4* b1v = (const float4*)b1;
  float4 bl = b1v[half * 2], bh = b1v[half * 2 + 1];
  float r[8];
  r[0] = fmaxf(fmaf(dv, acc[0] + self[0], bl.x), 0.f);
  r[1] = fmaxf(fmaf(dv, acc[1] + self[1], bl.y), 0.f);
  r[2] = fmaxf(fmaf(dv, acc[2] + self[2], bl.z), 0.f);
  r[3] = fmaxf(fmaf(dv, acc[3] + self[3], bl.w), 0.f);
  r[4] = fmaxf(fmaf(dv, acc[4] + self[4], bh.x), 0.f);
  r[5] = fmaxf(fmaf(dv, acc[5] + self[5], bh.y), 0.f);
  r[6] = fmaxf(fmaf(dv, acc[6] + self[6], bh.z), 0.f);
  r[7] = fmaxf(fmaf(dv, acc[7] + self[7], bh.w), 0.f);
  const float* w2 = W2 + half * 8 * CDIM;
  float p[CDIM];
  #pragma unroll
  for (int c = 0; c < CDIM; ++c){
    float s = 0.f;
    #pragma unroll
    for (int k = 0; k < 8; ++k) s = fmaf(r[k], w2[k * CDIM + c], s);
    p[c] = s;
  }
  #pragma unroll
  for (int c = 0; c < CDIM; ++c) p[c] += __shfl_xor(p[c], 1);
  if (lane == 0){
    unsigned short o[8];
    #pragma unroll
    for (int c = 0; c < CDIM; ++c) o[c] = f2bf(dv * p[c]);
    o[5] = 0; o[6] = 0; o[7] = 0;
    uint4 v; __builtin_memcpy(&v, o, 16);
    *(uint4*)(hs2 + (size_t)i * 8) = v;
  }
}

// ---- conv2 aggregate + b2 + mlp + log_softmax -> out [N][5] f32
__global__ __launch_bounds__(256) void k_agg2(const unsigned short* __restrict__ hs2,
    const int* __restrict__ rowptr, const int* __restrict__ ssrc,
    const float* __restrict__ dinv, const float* __restrict__ b2,
    const float* __restrict__ W3, const float* __restrict__ b3,
    const float* __restrict__ W4, const float* __restrict__ b4,
    float* __restrict__ out, int n){
  int lane = threadIdx.x & 63;
  int i = blockIdx.x * 4 + (threadIdx.x >> 6);
  if (i >= n) return;
  int beg = rowptr[i], end = rowptr[i + 1];
  const uint4* hv = (const uint4*)hs2;                 // row = 1 uint4
  float acc[CDIM];
  #pragma unroll
  for (int k = 0; k < CDIM; ++k) acc[k] = 0.f;
  for (int e = beg + lane; e < end; e += 64){
    int src = ssrc[e];
    uint4 v = hv[src];
    acc[0] += ulo(v.x); acc[1] += uhi(v.x);
    acc[2] += ulo(v.y); acc[3] += uhi(v.y);
    acc[4] += ulo(v.z);
  }
  #pragma unroll
  for (int off = 1; off < 64; off <<= 1){
    #pragma unroll
    for (int k = 0; k < CDIM; ++k) acc[k] += __shfl_xor(acc[k], off);
  }
  float dv = dinv[i];
  uint4 sv = hv[i];
  float a0 = fmaf(dv, acc[0] + ulo(sv.x), b2[0]);
  float a1 = fmaf(dv, acc[1] + uhi(sv.x), b2[1]);
  float a2 = fmaf(dv, acc[2] + ulo(sv.y), b2[2]);
  float a3 = fmaf(dv, acc[3] + uhi(sv.y), b2[3]);
  float a4 = fmaf(dv, acc[4] + ulo(sv.z), b2[4]);
  int m = lane & 31;
  float h3 = b3[m];
  h3 = fmaf(a0, W3[0 * 32 + m], h3);
  h3 = fmaf(a1, W3[1 * 32 + m], h3);
  h3 = fmaf(a2, W3[2 * 32 + m], h3);
  h3 = fmaf(a3, W3[3 * 32 + m], h3);
  h3 = fmaf(a4, W3[4 * 32 + m], h3);
  h3 = fmaxf(h3, 0.f);
  float q0 = h3 * W4[m * CDIM + 0], q1 = h3 * W4[m * CDIM + 1], q2 = h3 * W4[m * CDIM + 2];
  float q3 = h3 * W4[m * CDIM + 3], q4 = h3 * W4[m * CDIM + 4];
  #pragma unroll
  for (int off = 1; off < 32; off <<= 1){
    q0 += __shfl_xor(q0, off); q1 += __shfl_xor(q1, off); q2 += __shfl_xor(q2, off);
    q3 += __shfl_xor(q3, off); q4 += __shfl_xor(q4, off);
  }
  q0 += b4[0]; q1 += b4[1]; q2 += b4[2]; q3 += b4[3]; q4 += b4[4];
  float mx = fmaxf(fmaxf(fmaxf(q0, q1), fmaxf(q2, q3)), q4);
  float sum = expf(q0 - mx) + expf(q1 - mx) + expf(q2 - mx) + expf(q3 - mx) + expf(q4 - mx);
  float lse = mx + logf(sum);
  if (lane < CDIM){
    float v = q0;
    if (lane == 1) v = q1;
    if (lane == 2) v = q2;
    if (lane == 3) v = q3;
    if (lane == 4) v = q4;
    out[(size_t)i * CDIM + lane] = v - lse;
  }
}

extern "C" void kernel_launch(void* const* d_in, const int* in_sizes, int n_in,
                              void* d_out, int out_size, void* d_ws, size_t ws_size,
                              hipStream_t stream){
  const float* x  = (const float*)d_in[0];
  const int*   ei = (const int*)d_in[1];
  const float* W1 = (const float*)d_in[2];
  const float* b1 = (const float*)d_in[3];
  const float* W2 = (const float*)d_in[4];
  const float* b2 = (const float*)d_in[5];
  const float* W3 = (const float*)d_in[6];
  const float* b3 = (const float*)d_in[7];
  const float* W4 = (const float*)d_in[8];
  const float* b4 = (const float*)d_in[9];
  float* out = (float*)d_out;

  int N = in_sizes[0] / F_IN;
  int E = in_sizes[1] / 2;
  int NPB = (N + NB - 1) / NB;      // nodes per bucket (98 for N=100000)

  char* ws = (char*)d_ws;
  size_t off = 0;
  auto alloc = [&](size_t bytes) -> char* {
    char* p = ws + off;
    off += (bytes + 255) & ~(size_t)255;
    return p;
  };
  int* flag  = (int*)alloc(4);
  int* gwp   = (int*)alloc((size_t)NB * GWP_STRIDE * 4);
  int* bbase = (int*)alloc(((size_t)NB + 1) * 4);
  int* rowptr= (int*)alloc(((size_t)N + 1) * 4);
  float* dinv= (float*)alloc((size_t)N * 4);
  unsigned short* pw = (unsigned short*)alloc((size_t)F_IN * HDIM * 2);
  int* pairs = (int*)alloc((size_t)NB * SEG * 4);   // segmented, 32 MB
  int* ssrc  = (int*)alloc((size_t)E * 4);
  unsigned short* hs1 = (unsigned short*)alloc((size_t)N * HDIM * 2);
  unsigned short* hs2 = (unsigned short*)alloc((size_t)N * 8 * 2);
  (void)ws_size; (void)n_in; (void)out_size;

  k_detect<<<1, 1024, 0, stream>>>(ei, flag, gwp, E);
  k_packW1<<<1, 256, 0, stream>>>(W1, pw);
  int sblocks = (E + SCHUNK - 1) / SCHUNK;
  k_binscatter<<<sblocks, 1024, 0, stream>>>(ei, flag, gwp, pairs, E, NPB);
  k_scanNB<<<1, 1024, 0, stream>>>(gwp, bbase, NB);
  k_bucket<<<NB, 512, 0, stream>>>(pairs, bbase, rowptr, dinv, ssrc, NPB, N, E);
  k_gemm1<<<768, 256, 0, stream>>>(x, pw, dinv, hs1, N);
  k_agg1<<<(N + 3) / 4, 256, 0, stream>>>(hs1, rowptr, ssrc, dinv, b1, W2, hs2, N);
  k_agg2<<<(N + 3) / 4, 256, 0, stream>>>(hs2, rowptr, ssrc, dinv, b2, W3, b3, W4, b4, out, N);
}